// Round 1
// baseline (919.218 us; speedup 1.0000x reference)
//
#include <hip/hip_runtime.h>
#include <cstdint>
#include <math.h>

#define TT 2048
#define DD 2048
#define NH 16
#define NKV 4
#define HD 128
#define SCALE_F 0.08838834764831845f

// V-tile LDS swizzle: logical f32 word L -> physical word, spreads stride-8-word
// accesses across bank groups (2-way max instead of 4-way).
#define VROW 140
#define VSW(L) ((L) + 4*((L)>>5))

__device__ __forceinline__ int dot4(int a, int b, int c) {
  return __builtin_amdgcn_sdot4(a, b, c, false);
}

// ---------------------------------------------------------------------------
// Kernel 1: rowwise symmetric int8 quantization for x, wq, wk, wv.
// One block per row (row length DD=2048), 256 threads, 8 elems/thread.
// ---------------------------------------------------------------------------
__global__ __launch_bounds__(256)
void quant_rows_kernel(const float* __restrict__ x, const float* __restrict__ wq,
                       const float* __restrict__ wk, const float* __restrict__ wv,
                       int8_t* __restrict__ qx, float* __restrict__ xs,
                       int8_t* __restrict__ qwq, float* __restrict__ wqs,
                       int8_t* __restrict__ qwk, float* __restrict__ wks,
                       int8_t* __restrict__ qwv, float* __restrict__ wvs) {
  int r = blockIdx.x;
  const float* src; int8_t* dst; float* sc; int row;
  if (r < 2048)      { src = x;  dst = qx;  sc = xs;  row = r; }
  else if (r < 4096) { src = wq; dst = qwq; sc = wqs; row = r - 2048; }
  else if (r < 4608) { src = wk; dst = qwk; sc = wks; row = r - 4096; }
  else               { src = wv; dst = qwv; sc = wvs; row = r - 4608; }
  src += (size_t)row * DD; dst += (size_t)row * DD;
  int tid = threadIdx.x;
  float4 v0 = ((const float4*)src)[2*tid];
  float4 v1 = ((const float4*)src)[2*tid+1];
  float m = fmaxf(fmaxf(fmaxf(fabsf(v0.x), fabsf(v0.y)), fmaxf(fabsf(v0.z), fabsf(v0.w))),
                  fmaxf(fmaxf(fabsf(v1.x), fabsf(v1.y)), fmaxf(fabsf(v1.z), fabsf(v1.w))));
  #pragma unroll
  for (int off = 1; off < 64; off <<= 1) m = fmaxf(m, __shfl_xor(m, off));
  __shared__ float wmax[4];
  if ((tid & 63) == 0) wmax[tid >> 6] = m;
  __syncthreads();
  m = fmaxf(fmaxf(wmax[0], wmax[1]), fmaxf(wmax[2], wmax[3]));
  float s = fmaxf(m / 127.0f, 1e-8f);
  if (tid == 0) sc[row] = s;
  float vv[8] = {v0.x, v0.y, v0.z, v0.w, v1.x, v1.y, v1.z, v1.w};
  uint32_t p0 = 0, p1 = 0;
  #pragma unroll
  for (int i = 0; i < 4; ++i) {
    int q = (int)fminf(fmaxf(rintf(vv[i] / s), -127.0f), 127.0f);
    p0 |= ((uint32_t)q & 0xffu) << (8*i);
  }
  #pragma unroll
  for (int i = 0; i < 4; ++i) {
    int q = (int)fminf(fmaxf(rintf(vv[4+i] / s), -127.0f), 127.0f);
    p1 |= ((uint32_t)q & 0xffu) << (8*i);
  }
  ((uint2*)dst)[tid] = make_uint2(p0, p1);
}

// ---------------------------------------------------------------------------
// Kernel 2: fused int8 projection GEMM + dequant + RoPE + rowwise requant.
// blockIdx.y = global head 0..23 (0-15 Q, 16-19 K, 20-23 V).
// Tile: 128 t-rows x 128 head-dims, K swept in 128-byte chunks.
// 256 threads, 8x8 micro-tile with stride-16 row/col assignment
// (keeps all hot LDS reads <=2-way bank aliased).
// ---------------------------------------------------------------------------
__global__ __launch_bounds__(256)
void proj_kernel(const int8_t* __restrict__ qx, const float* __restrict__ xs,
                 const int8_t* __restrict__ qwq, const float* __restrict__ wqs,
                 const int8_t* __restrict__ qwk, const float* __restrict__ wks,
                 const int8_t* __restrict__ qwv, const float* __restrict__ wvs,
                 int8_t* __restrict__ qq, float* __restrict__ qsc_out,
                 int8_t* __restrict__ kq, float* __restrict__ ksc_out,
                 int8_t* __restrict__ vq, float* __restrict__ vsc_out) {
  int gh = blockIdx.y;
  int t0 = blockIdx.x * 128;
  const int8_t* w; const float* wsc; int8_t* outq; float* outs; bool doRope;
  if (gh < NH) {
    w = qwq + (size_t)gh*HD*DD; wsc = wqs + gh*HD;
    outq = qq + (size_t)gh*TT*HD; outs = qsc_out + (size_t)gh*TT; doRope = true;
  } else if (gh < NH + NKV) {
    int hh = gh - NH;
    w = qwk + (size_t)hh*HD*DD; wsc = wks + hh*HD;
    outq = kq + (size_t)hh*TT*HD; outs = ksc_out + (size_t)hh*TT; doRope = true;
  } else {
    int hh = gh - NH - NKV;
    w = qwv + (size_t)hh*HD*DD; wsc = wvs + hh*HD;
    outq = vq + (size_t)hh*TT*HD; outs = vsc_out + (size_t)hh*TT; doRope = false;
  }

  __shared__ int8_t As[128][144];
  __shared__ int8_t Bs[128][144];
  int tid = threadIdx.x;
  int tg = tid >> 4;   // rows tg + 16*i
  int og = tid & 15;   // cols og + 16*j

  int acc[8][8];
  #pragma unroll
  for (int i = 0; i < 8; ++i)
    #pragma unroll
    for (int j = 0; j < 8; ++j) acc[i][j] = 0;

  for (int kt = 0; kt < DD/128; ++kt) {
    #pragma unroll
    for (int i = 0; i < 4; ++i) {
      int idx = tid + i*256, r = idx >> 3, c = idx & 7;
      *(int4*)&As[r][c*16] = *(const int4*)&qx[(size_t)(t0 + r)*DD + kt*128 + c*16];
      *(int4*)&Bs[r][c*16] = *(const int4*)&w[(size_t)r*DD + kt*128 + c*16];
    }
    __syncthreads();
    #pragma unroll
    for (int w4 = 0; w4 < 8; ++w4) {
      int4 bregs[8];
      #pragma unroll
      for (int j = 0; j < 8; ++j) bregs[j] = *(const int4*)&Bs[og + 16*j][w4*16];
      #pragma unroll
      for (int i = 0; i < 8; ++i) {
        int4 a = *(const int4*)&As[tg + 16*i][w4*16];
        #pragma unroll
        for (int j = 0; j < 8; ++j) {
          int v = acc[i][j];
          v = dot4(a.x, bregs[j].x, v);
          v = dot4(a.y, bregs[j].y, v);
          v = dot4(a.z, bregs[j].z, v);
          v = dot4(a.w, bregs[j].w, v);
          acc[i][j] = v;
        }
      }
    }
    __syncthreads();
  }

  // Epilogue: dequant -> (RoPE) -> rowwise requant to int8
  float y[8][8];
  #pragma unroll
  for (int i = 0; i < 8; ++i) {
    float xsi = xs[t0 + tg + 16*i];
    #pragma unroll
    for (int j = 0; j < 8; ++j)
      y[i][j] = ((float)acc[i][j] * xsi) * wsc[og + 16*j];
  }
  if (doRope) {
    float invf[4];
    #pragma unroll
    for (int j = 0; j < 4; ++j) {
      float e = (float)(og + 16*j) * (1.0f/64.0f);   // 2d/128 with d = og+16j (<64)
      invf[j] = 1.0f / powf(1000000.0f, e);
    }
    #pragma unroll
    for (int i = 0; i < 8; ++i) {
      float trow = (float)(t0 + tg + 16*i);
      #pragma unroll
      for (int j = 0; j < 4; ++j) {
        float ang = trow * invf[j];
        float sn, cs;
        sincosf(ang, &sn, &cs);
        float lo = y[i][j], hi = y[i][j+4];
        y[i][j]   = lo*cs - hi*sn;   // d<64: partner = -q[d+64]
        y[i][j+4] = hi*cs + lo*sn;   // d>=64: partner = q[d-64]
      }
    }
  }
  #pragma unroll
  for (int i = 0; i < 8; ++i) {
    float mx = fabsf(y[i][0]);
    #pragma unroll
    for (int j = 1; j < 8; ++j) mx = fmaxf(mx, fabsf(y[i][j]));
    mx = fmaxf(mx, __shfl_xor(mx, 1));
    mx = fmaxf(mx, __shfl_xor(mx, 2));
    mx = fmaxf(mx, __shfl_xor(mx, 4));
    mx = fmaxf(mx, __shfl_xor(mx, 8));
    float s = fmaxf(mx / 127.0f, 1e-8f);
    if (og == 0) outs[t0 + tg + 16*i] = s;
    #pragma unroll
    for (int j = 0; j < 8; ++j) {
      int qv = (int)fminf(fmaxf(rintf(y[i][j] / s), -127.0f), 127.0f);
      As[tg + 16*i][og + 16*j] = (int8_t)qv;
    }
  }
  __syncthreads();
  #pragma unroll
  for (int i = 0; i < 4; ++i) {
    int idx = tid + i*256, r = idx >> 3, c = idx & 7;
    *(int4*)&outq[(size_t)(t0 + r)*HD + c*16] = *(const int4*)&As[r][c*16];
  }
}

// ---------------------------------------------------------------------------
// Kernel 3: flash-style causal int8 attention.
// Grid: (64 q-blocks of 32 rows, 16 heads). 256 threads.
// Per K-tile (64 rows): sdot4 scores -> online softmax -> f32 PV with
// dequantized V (vq*vs) staged swizzled in LDS.
// Row ownership is wave-local under both score (2q x 4k) and PV (2q x 8d)
// mappings: qg = tid>>4 owns rows 2qg, 2qg+1.
// ---------------------------------------------------------------------------
__global__ __launch_bounds__(256)
void attn_kernel(const int8_t* __restrict__ qq, const float* __restrict__ qsc_in,
                 const int8_t* __restrict__ kq, const float* __restrict__ ksc_in,
                 const int8_t* __restrict__ vq, const float* __restrict__ vsc_in,
                 float* __restrict__ ao) {
  int h   = blockIdx.y;
  int qb  = blockIdx.x;
  int hk  = h >> 2;            // GQA: repeat(4) -> orig head = h/4
  int qb0 = qb * 32;
  int nkt = qb / 2 + 1;

  __shared__ int8_t Qs[32][144];
  __shared__ int8_t Ks[64][144];
  __shared__ float  Vs[64 * VROW];
  __shared__ float  Pt[64 * 34];   // transposed P: Pt[k][q]
  __shared__ float  mrow[32], lrow[32], crow[32], qsc[32];

  int tid = threadIdx.x;
  int qg = tid >> 4;    // rows 2qg, 2qg+1
  int lg = tid & 15;    // score: k-cols lg+16j ; PV: d-cols lg*8..+7

  { int r = tid >> 3, c = tid & 7;
    *(int4*)&Qs[r][c*16] = *(const int4*)&qq[((size_t)h*TT + qb0 + r)*HD + c*16]; }
  if (tid < 32) {
    mrow[tid] = -INFINITY; lrow[tid] = 0.0f;
    qsc[tid] = qsc_in[(size_t)h*TT + qb0 + tid];
  }
  __syncthreads();

  int4 q0[8], q1[8];
  #pragma unroll
  for (int w4 = 0; w4 < 8; ++w4) {
    q0[w4] = *(const int4*)&Qs[2*qg][w4*16];
    q1[w4] = *(const int4*)&Qs[2*qg+1][w4*16];
  }
  float qsc0 = qsc[2*qg], qsc1 = qsc[2*qg+1];
  int qrow0 = qb0 + 2*qg, qrow1 = qrow0 + 1;

  float acc[2][8];
  #pragma unroll
  for (int r = 0; r < 2; ++r)
    #pragma unroll
    for (int j = 0; j < 8; ++j) acc[r][j] = 0.0f;

  for (int kt = 0; kt < nkt; ++kt) {
    int k0 = kt * 64;
    __syncthreads();   // previous iteration done with Ks/Vs
    #pragma unroll
    for (int i = 0; i < 2; ++i) {
      int idx = tid + i*256, r = idx >> 3, c = idx & 7;
      *(int4*)&Ks[r][c*16] = *(const int4*)&kq[((size_t)hk*TT + k0 + r)*HD + c*16];
      int4 vb = *(const int4*)&vq[((size_t)hk*TT + k0 + r)*HD + c*16];
      float vsr = vsc_in[(size_t)hk*TT + k0 + r];
      const int vw[4] = {vb.x, vb.y, vb.z, vb.w};
      #pragma unroll
      for (int m = 0; m < 4; ++m) {
        int wv = vw[m];
        float4 f;
        f.x = (float)((wv << 24) >> 24) * vsr;
        f.y = (float)((wv << 16) >> 24) * vsr;
        f.z = (float)((wv <<  8) >> 24) * vsr;
        f.w = (float)( wv        >> 24) * vsr;
        int L = c*16 + 4*m;
        *(float4*)&Vs[r*VROW + VSW(L)] = f;
      }
    }
    __syncthreads();

    // ---- scores: 2 q-rows x 4 k-cols per thread ----
    float sf[2][4];
    #pragma unroll
    for (int j = 0; j < 4; ++j) {
      int kc = lg + 16*j;
      int d0 = 0, d1 = 0;
      #pragma unroll
      for (int w4 = 0; w4 < 8; ++w4) {
        int4 b = *(const int4*)&Ks[kc][w4*16];
        d0 = dot4(q0[w4].x, b.x, d0); d0 = dot4(q0[w4].y, b.y, d0);
        d0 = dot4(q0[w4].z, b.z, d0); d0 = dot4(q0[w4].w, b.w, d0);
        d1 = dot4(q1[w4].x, b.x, d1); d1 = dot4(q1[w4].y, b.y, d1);
        d1 = dot4(q1[w4].z, b.z, d1); d1 = dot4(q1[w4].w, b.w, d1);
      }
      int kg = k0 + kc;
      float ksv = ksc_in[(size_t)hk*TT + kg];
      float s0 = (((float)d0 * qsc0) * ksv) * SCALE_F;
      float s1 = (((float)d1 * qsc1) * ksv) * SCALE_F;
      sf[0][j] = (kg <= qrow0) ? s0 : -INFINITY;
      sf[1][j] = (kg <= qrow1) ? s1 : -INFINITY;
    }

    // ---- online softmax bookkeeping (rows are wave-local) ----
    float mt0 = fmaxf(fmaxf(sf[0][0], sf[0][1]), fmaxf(sf[0][2], sf[0][3]));
    float mt1 = fmaxf(fmaxf(sf[1][0], sf[1][1]), fmaxf(sf[1][2], sf[1][3]));
    #pragma unroll
    for (int off = 1; off < 16; off <<= 1) {
      mt0 = fmaxf(mt0, __shfl_xor(mt0, off));
      mt1 = fmaxf(mt1, __shfl_xor(mt1, off));
    }
    float mold0 = mrow[2*qg],   mold1 = mrow[2*qg+1];
    float mnew0 = fmaxf(mold0, mt0), mnew1 = fmaxf(mold1, mt1);
    float corr0 = expf(mold0 - mnew0), corr1 = expf(mold1 - mnew1);
    float pr0[4], pr1[4];
    float ps0 = 0.0f, ps1 = 0.0f;
    #pragma unroll
    for (int j = 0; j < 4; ++j) {
      pr0[j] = expf(sf[0][j] - mnew0); ps0 += pr0[j];
      pr1[j] = expf(sf[1][j] - mnew1); ps1 += pr1[j];
    }
    #pragma unroll
    for (int off = 1; off < 16; off <<= 1) {
      ps0 += __shfl_xor(ps0, off);
      ps1 += __shfl_xor(ps1, off);
    }
    if (lg == 0) {
      mrow[2*qg]   = mnew0; crow[2*qg]   = corr0; lrow[2*qg]   = lrow[2*qg]*corr0 + ps0;
      mrow[2*qg+1] = mnew1; crow[2*qg+1] = corr1; lrow[2*qg+1] = lrow[2*qg+1]*corr1 + ps1;
    }
    #pragma unroll
    for (int j = 0; j < 4; ++j) {
      Pt[(lg + 16*j)*34 + 2*qg]     = pr0[j];
      Pt[(lg + 16*j)*34 + 2*qg + 1] = pr1[j];
    }
    __syncthreads();

    // ---- PV: 2 q-rows x 8 d-cols per thread ----
    float c0 = crow[2*qg], c1 = crow[2*qg+1];
    #pragma unroll
    for (int j = 0; j < 8; ++j) { acc[0][j] *= c0; acc[1][j] *= c1; }
    int vbase = VSW(lg*8);
    #pragma unroll 4
    for (int k = 0; k < 64; ++k) {
      float2 pp = *(const float2*)&Pt[k*34 + 2*qg];
      const float* vrow = &Vs[k*VROW + vbase];
      float4 va = *(const float4*)vrow;
      float4 vb = *(const float4*)(vrow + 4);
      acc[0][0] = fmaf(pp.x, va.x, acc[0][0]); acc[0][1] = fmaf(pp.x, va.y, acc[0][1]);
      acc[0][2] = fmaf(pp.x, va.z, acc[0][2]); acc[0][3] = fmaf(pp.x, va.w, acc[0][3]);
      acc[0][4] = fmaf(pp.x, vb.x, acc[0][4]); acc[0][5] = fmaf(pp.x, vb.y, acc[0][5]);
      acc[0][6] = fmaf(pp.x, vb.z, acc[0][6]); acc[0][7] = fmaf(pp.x, vb.w, acc[0][7]);
      acc[1][0] = fmaf(pp.y, va.x, acc[1][0]); acc[1][1] = fmaf(pp.y, va.y, acc[1][1]);
      acc[1][2] = fmaf(pp.y, va.z, acc[1][2]); acc[1][3] = fmaf(pp.y, va.w, acc[1][3]);
      acc[1][4] = fmaf(pp.y, vb.x, acc[1][4]); acc[1][5] = fmaf(pp.y, vb.y, acc[1][5]);
      acc[1][6] = fmaf(pp.y, vb.z, acc[1][6]); acc[1][7] = fmaf(pp.y, vb.w, acc[1][7]);
    }
  }

  float i0 = 1.0f / lrow[2*qg];
  float i1 = 1.0f / lrow[2*qg+1];
  size_t ob = (size_t)qrow0*DD + (size_t)h*HD + lg*8;
  *(float4*)&ao[ob]        = make_float4(acc[0][0]*i0, acc[0][1]*i0, acc[0][2]*i0, acc[0][3]*i0);
  *(float4*)&ao[ob + 4]    = make_float4(acc[0][4]*i0, acc[0][5]*i0, acc[0][6]*i0, acc[0][7]*i0);
  *(float4*)&ao[ob + DD]   = make_float4(acc[1][0]*i1, acc[1][1]*i1, acc[1][2]*i1, acc[1][3]*i1);
  *(float4*)&ao[ob + DD+4] = make_float4(acc[1][4]*i1, acc[1][5]*i1, acc[1][6]*i1, acc[1][7]*i1);
}

// ---------------------------------------------------------------------------
// Kernel 4: f32 output projection  out[t,o] = sum_d ao[t,d] * wo[o,d].
// Tile 64t x 128o, BK=32, 256 threads, 4x8 micro-tile, K-major LDS.
// ---------------------------------------------------------------------------
__global__ __launch_bounds__(256)
void wo_gemm_kernel(const float* __restrict__ ao, const float* __restrict__ wom,
                    float* __restrict__ outp) {
  int o0 = blockIdx.x * 128;
  int t0 = blockIdx.y * 64;
  __shared__ float As[32][68];    // As[k][t]
  __shared__ float Bs[32][132];   // Bs[k][o]
  int tid = threadIdx.x;
  int tg = tid >> 4;   // t rows tg*4 + i
  int og = tid & 15;   // o cols og*8 + j
  float acc[4][8];
  #pragma unroll
  for (int i = 0; i < 4; ++i)
    #pragma unroll
    for (int j = 0; j < 8; ++j) acc[i][j] = 0.0f;

  for (int kt = 0; kt < 64; ++kt) {
    int k0 = kt * 32;
    #pragma unroll
    for (int i = 0; i < 2; ++i) {
      int idx = tid + i*256, r = idx >> 3, c4 = (idx & 7)*4;
      float4 a = *(const float4*)&ao[(size_t)(t0 + r)*DD + k0 + c4];
      As[c4+0][r] = a.x; As[c4+1][r] = a.y; As[c4+2][r] = a.z; As[c4+3][r] = a.w;
    }
    #pragma unroll
    for (int i = 0; i < 4; ++i) {
      int idx = tid + i*256, r = idx >> 3, c4 = (idx & 7)*4;
      float4 b = *(const float4*)&wom[(size_t)(o0 + r)*DD + k0 + c4];
      Bs[c4+0][r] = b.x; Bs[c4+1][r] = b.y; Bs[c4+2][r] = b.z; Bs[c4+3][r] = b.w;
    }
    __syncthreads();
    #pragma unroll 8
    for (int kk = 0; kk < 32; ++kk) {
      float4 a  = *(const float4*)&As[kk][tg*4];
      float4 b0 = *(const float4*)&Bs[kk][og*8];
      float4 b1 = *(const float4*)&Bs[kk][og*8 + 4];
      float av[4] = {a.x, a.y, a.z, a.w};
      float bv[8] = {b0.x, b0.y, b0.z, b0.w, b1.x, b1.y, b1.z, b1.w};
      #pragma unroll
      for (int i = 0; i < 4; ++i)
        #pragma unroll
        for (int j = 0; j < 8; ++j)
          acc[i][j] = fmaf(av[i], bv[j], acc[i][j]);
    }
    __syncthreads();
  }
  #pragma unroll
  for (int i = 0; i < 4; ++i) {
    size_t ob = (size_t)(t0 + tg*4 + i)*DD + o0 + og*8;
    *(float4*)&outp[ob]     = make_float4(acc[i][0], acc[i][1], acc[i][2], acc[i][3]);
    *(float4*)&outp[ob + 4] = make_float4(acc[i][4], acc[i][5], acc[i][6], acc[i][7]);
  }
}

// ---------------------------------------------------------------------------
extern "C" void kernel_launch(void* const* d_in, const int* in_sizes, int n_in,
                              void* d_out, int out_size, void* d_ws, size_t ws_size,
                              hipStream_t stream) {
  (void)in_sizes; (void)n_in; (void)out_size; (void)ws_size;
  const float* x  = (const float*)d_in[0];
  const float* wq = (const float*)d_in[1];
  const float* wk = (const float*)d_in[2];
  const float* wv = (const float*)d_in[3];
  const float* wo = (const float*)d_in[4];
  float* out = (float*)d_out;

  char* ws = (char*)d_ws;
  const size_t MB = 1024*1024;
  int8_t* qx  = (int8_t*)(ws);
  int8_t* qwq = (int8_t*)(ws + 4*MB);
  int8_t* qwk = (int8_t*)(ws + 8*MB);
  int8_t* qwv = (int8_t*)(ws + 9*MB);
  int8_t* qqp = (int8_t*)(ws + 10*MB);   // [16][2048][128]
  int8_t* kqp = (int8_t*)(ws + 14*MB);   // [4][2048][128]
  int8_t* vqp = (int8_t*)(ws + 15*MB);   // [4][2048][128]
  float* fb  = (float*)(ws + 16*MB);
  float* xs  = fb;                 // 2048
  float* wqs = xs + 2048;          // 2048
  float* wks = wqs + 2048;         // 512
  float* wvs = wks + 512;          // 512
  float* qsc = wvs + 512;          // 16*2048
  float* ksc = qsc + (size_t)NH*TT;   // 4*2048
  float* vsc = ksc + (size_t)NKV*TT;  // 4*2048
  float* ao  = vsc + (size_t)NKV*TT;  // 2048*2048

  quant_rows_kernel<<<5120, 256, 0, stream>>>(x, wq, wk, wv,
                                              qx, xs, qwq, wqs, qwk, wks, qwv, wvs);
  proj_kernel<<<dim3(TT/128, NH + 2*NKV), 256, 0, stream>>>(
      qx, xs, qwq, wqs, qwk, wks, qwv, wvs,
      qqp, qsc, kqp, ksc, vqp, vsc);
  attn_kernel<<<dim3(TT/32, NH), 256, 0, stream>>>(
      qqp, qsc, kqp, ksc, vqp, vsc, ao);
  wo_gemm_kernel<<<dim3(DD/128, TT/64), 256, 0, stream>>>(ao, wo, out);
}

// Round 3
// 636.576 us; speedup vs baseline: 1.4440x; 1.4440x over previous
//
#include <hip/hip_runtime.h>
#include <cstdint>
#include <math.h>

#define TT 2048
#define DD 2048
#define NH 16
#define NKV 4
#define HD 128
#define SCALE_F 0.08838834764831845f
#define LOG2E 1.4426950408889634f

typedef int   i32x4 __attribute__((ext_vector_type(4)));
typedef float f32x4 __attribute__((ext_vector_type(4)));
typedef short s16x8 __attribute__((ext_vector_type(8)));

__device__ __forceinline__ int dot4(int a, int b, int c) {
  return __builtin_amdgcn_sdot4(a, b, c, false);
}
__device__ __forceinline__ i32x4 mfma_i8(i32x4 a, i32x4 b, i32x4 c) {
  return __builtin_amdgcn_mfma_i32_16x16x64_i8(a, b, c, 0, 0, 0);
}
__device__ __forceinline__ f32x4 mfma_bf16(s16x8 a, s16x8 b, f32x4 c) {
  return __builtin_amdgcn_mfma_f32_16x16x32_bf16(a, b, c, 0, 0, 0);
}
__device__ __forceinline__ uint32_t fbits(float f) {
  union { float f; uint32_t u; } x; x.f = f; return x.u;
}

// ---------------------------------------------------------------------------
// Kernel 1: rowwise symmetric int8 quantization for x, wq, wk, wv.
// ---------------------------------------------------------------------------
__global__ __launch_bounds__(256)
void quant_rows_kernel(const float* __restrict__ x, const float* __restrict__ wq,
                       const float* __restrict__ wk, const float* __restrict__ wv,
                       int8_t* __restrict__ qx, float* __restrict__ xs,
                       int8_t* __restrict__ qwq, float* __restrict__ wqs,
                       int8_t* __restrict__ qwk, float* __restrict__ wks,
                       int8_t* __restrict__ qwv, float* __restrict__ wvs) {
  int r = blockIdx.x;
  const float* src; int8_t* dst; float* sc; int row;
  if (r < 2048)      { src = x;  dst = qx;  sc = xs;  row = r; }
  else if (r < 4096) { src = wq; dst = qwq; sc = wqs; row = r - 2048; }
  else if (r < 4608) { src = wk; dst = qwk; sc = wks; row = r - 4096; }
  else               { src = wv; dst = qwv; sc = wvs; row = r - 4608; }
  src += (size_t)row * DD; dst += (size_t)row * DD;
  int tid = threadIdx.x;
  float4 v0 = ((const float4*)src)[2*tid];
  float4 v1 = ((const float4*)src)[2*tid+1];
  float m = fmaxf(fmaxf(fmaxf(fabsf(v0.x), fabsf(v0.y)), fmaxf(fabsf(v0.z), fabsf(v0.w))),
                  fmaxf(fmaxf(fabsf(v1.x), fabsf(v1.y)), fmaxf(fabsf(v1.z), fabsf(v1.w))));
  #pragma unroll
  for (int off = 1; off < 64; off <<= 1) m = fmaxf(m, __shfl_xor(m, off));
  __shared__ float wmax[4];
  if ((tid & 63) == 0) wmax[tid >> 6] = m;
  __syncthreads();
  m = fmaxf(fmaxf(wmax[0], wmax[1]), fmaxf(wmax[2], wmax[3]));
  float s = fmaxf(m / 127.0f, 1e-8f);
  if (tid == 0) sc[row] = s;
  float vv[8] = {v0.x, v0.y, v0.z, v0.w, v1.x, v1.y, v1.z, v1.w};
  uint32_t p0 = 0, p1 = 0;
  #pragma unroll
  for (int i = 0; i < 4; ++i) {
    int q = (int)fminf(fmaxf(rintf(vv[i] / s), -127.0f), 127.0f);
    p0 |= ((uint32_t)q & 0xffu) << (8*i);
  }
  #pragma unroll
  for (int i = 0; i < 4; ++i) {
    int q = (int)fminf(fmaxf(rintf(vv[4+i] / s), -127.0f), 127.0f);
    p1 |= ((uint32_t)q & 0xffu) << (8*i);
  }
  ((uint2*)dst)[tid] = make_uint2(p0, p1);
}

// ---------------------------------------------------------------------------
// Kernel 2: fused int8 projection GEMM + dequant + RoPE + rowwise requant.
// ---------------------------------------------------------------------------
__global__ __launch_bounds__(256)
void proj_kernel(const int8_t* __restrict__ qx, const float* __restrict__ xs,
                 const int8_t* __restrict__ qwq, const float* __restrict__ wqs,
                 const int8_t* __restrict__ qwk, const float* __restrict__ wks,
                 const int8_t* __restrict__ qwv, const float* __restrict__ wvs,
                 int8_t* __restrict__ qq, float* __restrict__ qsc_out,
                 int8_t* __restrict__ kq, float* __restrict__ ksc_out,
                 int8_t* __restrict__ vq, float* __restrict__ vsc_out) {
  int gh = blockIdx.y;
  int t0 = blockIdx.x * 128;
  const int8_t* w; const float* wsc; int8_t* outq; float* outs; bool doRope;
  if (gh < NH) {
    w = qwq + (size_t)gh*HD*DD; wsc = wqs + gh*HD;
    outq = qq + (size_t)gh*TT*HD; outs = qsc_out + (size_t)gh*TT; doRope = true;
  } else if (gh < NH + NKV) {
    int hh = gh - NH;
    w = qwk + (size_t)hh*HD*DD; wsc = wks + hh*HD;
    outq = kq + (size_t)hh*TT*HD; outs = ksc_out + (size_t)hh*TT; doRope = true;
  } else {
    int hh = gh - NH - NKV;
    w = qwv + (size_t)hh*HD*DD; wsc = wvs + hh*HD;
    outq = vq + (size_t)hh*TT*HD; outs = vsc_out + (size_t)hh*TT; doRope = false;
  }

  __shared__ int8_t As[128][144];
  __shared__ int8_t Bs[128][144];
  int tid = threadIdx.x;
  int tg = tid >> 4;
  int og = tid & 15;

  int acc[8][8];
  #pragma unroll
  for (int i = 0; i < 8; ++i)
    #pragma unroll
    for (int j = 0; j < 8; ++j) acc[i][j] = 0;

  for (int kt = 0; kt < DD/128; ++kt) {
    #pragma unroll
    for (int i = 0; i < 4; ++i) {
      int idx = tid + i*256, r = idx >> 3, c = idx & 7;
      *(int4*)&As[r][c*16] = *(const int4*)&qx[(size_t)(t0 + r)*DD + kt*128 + c*16];
      *(int4*)&Bs[r][c*16] = *(const int4*)&w[(size_t)r*DD + kt*128 + c*16];
    }
    __syncthreads();
    #pragma unroll
    for (int w4 = 0; w4 < 8; ++w4) {
      int4 bregs[8];
      #pragma unroll
      for (int j = 0; j < 8; ++j) bregs[j] = *(const int4*)&Bs[og + 16*j][w4*16];
      #pragma unroll
      for (int i = 0; i < 8; ++i) {
        int4 a = *(const int4*)&As[tg + 16*i][w4*16];
        #pragma unroll
        for (int j = 0; j < 8; ++j) {
          int v = acc[i][j];
          v = dot4(a.x, bregs[j].x, v);
          v = dot4(a.y, bregs[j].y, v);
          v = dot4(a.z, bregs[j].z, v);
          v = dot4(a.w, bregs[j].w, v);
          acc[i][j] = v;
        }
      }
    }
    __syncthreads();
  }

  float y[8][8];
  #pragma unroll
  for (int i = 0; i < 8; ++i) {
    float xsi = xs[t0 + tg + 16*i];
    #pragma unroll
    for (int j = 0; j < 8; ++j)
      y[i][j] = ((float)acc[i][j] * xsi) * wsc[og + 16*j];
  }
  if (doRope) {
    float invf[4];
    #pragma unroll
    for (int j = 0; j < 4; ++j) {
      float e = (float)(og + 16*j) * (1.0f/64.0f);
      invf[j] = 1.0f / powf(1000000.0f, e);
    }
    #pragma unroll
    for (int i = 0; i < 8; ++i) {
      float trow = (float)(t0 + tg + 16*i);
      #pragma unroll
      for (int j = 0; j < 4; ++j) {
        float ang = trow * invf[j];
        float sn, cs;
        sincosf(ang, &sn, &cs);
        float lo = y[i][j], hi = y[i][j+4];
        y[i][j]   = lo*cs - hi*sn;
        y[i][j+4] = hi*cs + lo*sn;
      }
    }
  }
  #pragma unroll
  for (int i = 0; i < 8; ++i) {
    float mx = fabsf(y[i][0]);
    #pragma unroll
    for (int j = 1; j < 8; ++j) mx = fmaxf(mx, fabsf(y[i][j]));
    mx = fmaxf(mx, __shfl_xor(mx, 1));
    mx = fmaxf(mx, __shfl_xor(mx, 2));
    mx = fmaxf(mx, __shfl_xor(mx, 4));
    mx = fmaxf(mx, __shfl_xor(mx, 8));
    float s = fmaxf(mx / 127.0f, 1e-8f);
    if (og == 0) outs[t0 + tg + 16*i] = s;
    #pragma unroll
    for (int j = 0; j < 8; ++j) {
      int qv = (int)fminf(fmaxf(rintf(y[i][j] / s), -127.0f), 127.0f);
      As[tg + 16*i][og + 16*j] = (int8_t)qv;
    }
  }
  __syncthreads();
  #pragma unroll
  for (int i = 0; i < 4; ++i) {
    int idx = tid + i*256, r = idx >> 3, c = idx & 7;
    *(int4*)&outq[(size_t)(t0 + r)*HD + c*16] = *(const int4*)&As[r][c*16];
  }
}

// ---------------------------------------------------------------------------
// Kernel 2b: convert int8 V to bf16 (exact: |v|<=127 fits bf16 mantissa).
// ---------------------------------------------------------------------------
__global__ __launch_bounds__(256)
void vcvt_kernel(const int8_t* __restrict__ vq, ushort* __restrict__ vbf) {
  int idx = blockIdx.x * 256 + threadIdx.x;     // 0..131071
  int2 raw = ((const int2*)vq)[idx];
  ushort o[8];
  #pragma unroll
  for (int j = 0; j < 4; ++j) {
    int v0 = (raw.x << (24 - 8*j)) >> 24;
    int v1 = (raw.y << (24 - 8*j)) >> 24;
    o[j]     = (ushort)(fbits((float)v0) >> 16);
    o[4 + j] = (ushort)(fbits((float)v1) >> 16);
  }
  s16x8 pack;
  #pragma unroll
  for (int j = 0; j < 8; ++j) pack[j] = (short)o[j];
  ((s16x8*)vbf)[idx] = pack;
}

// ---------------------------------------------------------------------------
// Kernel 3: MFMA flash attention.
// Grid (32 qb, 16 h), 256 threads = 4 waves, QB=64 (16 q-rows/wave), KB=64.
// Scores: mfma_i32_16x16x64_i8 (exact). PV: split-bf16 P' (=p*vs) x exact
// bf16 V via mfma_f32_16x16x32_bf16 (hi+lo -> ~f32 precision).
// ---------------------------------------------------------------------------
__global__ __launch_bounds__(256)
void attn_mfma_kernel(const int8_t* __restrict__ qq, const float* __restrict__ qsc_in,
                      const int8_t* __restrict__ kq, const float* __restrict__ ksc_in,
                      const ushort* __restrict__ vbf, const float* __restrict__ vsc_in,
                      float* __restrict__ ao) {
  int h = blockIdx.y;
  int qbIdx = (int)gridDim.x - 1 - (int)blockIdx.x;   // longest blocks first
  int hk = h >> 2;
  int qb0 = qbIdx * 64;
  int nkt = qbIdx + 1;

  __shared__ int8_t Ks[64 * 144];          // [k][d], 144B row stride
  __shared__ ushort Vt[128 * 72];          // [d][k] bf16, 72-elem row stride
  __shared__ float  Pf[4][16 * 68];        // per-wave P' f32 [q][k], stride 68

  int tid = threadIdx.x;
  int w  = tid >> 6;
  int l  = tid & 63;
  int lg = l & 15;
  int lh = l >> 4;

  // Q A-frags (16x16x64 i8): lane row = lg, k-bytes = lh*16 + {0,64}
  const int8_t* qp = &qq[((size_t)h*TT + qb0 + 16*w + lg)*HD + lh*16];
  i32x4 qa0 = *(const i32x4*)qp;
  i32x4 qa1 = *(const i32x4*)(qp + 64);

  // per-output-row scale (rows lh*4+rr), log2e folded for exp2 softmax
  float qsl[4];
  #pragma unroll
  for (int rr = 0; rr < 4; ++rr)
    qsl[rr] = qsc_in[(size_t)h*TT + qb0 + 16*w + lh*4 + rr] * (SCALE_F * LOG2E);

  float mrun[4] = {-1e30f, -1e30f, -1e30f, -1e30f};
  float lrun[4] = {0.f, 0.f, 0.f, 0.f};
  f32x4 acc_o[8];
  #pragma unroll
  for (int dt = 0; dt < 8; ++dt) acc_o[dt] = (f32x4){0.f, 0.f, 0.f, 0.f};

  for (int kt = 0; kt < nkt; ++kt) {
    int k0 = kt * 64;
    __syncthreads();
    // --- stage K (int8, padded rows) ---
    #pragma unroll
    for (int i = 0; i < 2; ++i) {
      int idx = tid + i*256, r = idx >> 3, c = idx & 7;
      *(i32x4*)&Ks[r*144 + c*16] =
          *(const i32x4*)&kq[((size_t)hk*TT + k0 + r)*HD + c*16];
    }
    // --- stage V transposed (bf16), packed k-pair b32 writes ---
    #pragma unroll
    for (int it = 0; it < 2; ++it) {
      int a = tid + it*256;
      int m2 = a & 31, d0 = (a >> 5) * 8;
      const ushort* vp = &vbf[((size_t)hk*TT + k0 + 2*m2)*HD + d0];
      s16x8 r0 = *(const s16x8*)vp;
      s16x8 r1 = *(const s16x8*)(vp + HD);
      #pragma unroll
      for (int j = 0; j < 8; ++j) {
        uint32_t pk = (uint32_t)(uint16_t)r0[j] | ((uint32_t)(uint16_t)r1[j] << 16);
        *(uint32_t*)&Vt[(d0 + j)*72 + 2*m2] = pk;
      }
    }
    __syncthreads();

    // --- scores: 4 k-tiles of 16, each 2 MFMAs over d=128 ---
    i32x4 sacc[4];
    #pragma unroll
    for (int t = 0; t < 4; ++t) sacc[t] = (i32x4){0, 0, 0, 0};
    #pragma unroll
    for (int t = 0; t < 4; ++t) {
      const int8_t* kp = &Ks[(lg + 16*t)*144 + lh*16];
      i32x4 b0 = *(const i32x4*)kp;
      i32x4 b1 = *(const i32x4*)(kp + 64);
      sacc[t] = mfma_i8(qa0, b0, sacc[t]);
      sacc[t] = mfma_i8(qa1, b1, sacc[t]);
    }

    float ksv[4], vsv[4];
    #pragma unroll
    for (int t = 0; t < 4; ++t) {
      ksv[t] = ksc_in[(size_t)hk*TT + k0 + lg + 16*t];
      vsv[t] = vsc_in[(size_t)hk*TT + k0 + lg + 16*t];
    }

    bool maskTile = (kt == nkt - 1);
    float sf[4][4];   // [rr][t], log2-domain
    #pragma unroll
    for (int t = 0; t < 4; ++t)
      #pragma unroll
      for (int rr = 0; rr < 4; ++rr) {
        float v = (float)sacc[t][rr] * qsl[rr] * ksv[t];
        if (maskTile) {
          int kkg = k0 + lg + 16*t;
          int qrow = qb0 + 16*w + lh*4 + rr;
          v = (kkg <= qrow) ? v : -1e30f;
        }
        sf[rr][t] = v;
      }

    // --- online softmax (16-lane groups) ---
    float corr[4], p[4][4];
    #pragma unroll
    for (int rr = 0; rr < 4; ++rr) {
      float rm = fmaxf(fmaxf(sf[rr][0], sf[rr][1]), fmaxf(sf[rr][2], sf[rr][3]));
      rm = fmaxf(rm, __shfl_xor(rm, 1));
      rm = fmaxf(rm, __shfl_xor(rm, 2));
      rm = fmaxf(rm, __shfl_xor(rm, 4));
      rm = fmaxf(rm, __shfl_xor(rm, 8));
      float mnew = fmaxf(mrun[rr], rm);
      corr[rr] = exp2f(mrun[rr] - mnew);
      mrun[rr] = mnew;
      float ps = 0.f;
      #pragma unroll
      for (int t = 0; t < 4; ++t) { p[rr][t] = exp2f(sf[rr][t] - mnew); ps += p[rr][t]; }
      ps += __shfl_xor(ps, 1);
      ps += __shfl_xor(ps, 2);
      ps += __shfl_xor(ps, 4);
      ps += __shfl_xor(ps, 8);
      lrun[rr] = lrun[rr]*corr[rr] + ps;
    }

    // --- write P' = p * vs to per-wave LDS (f32) ---
    #pragma unroll
    for (int rr = 0; rr < 4; ++rr)
      #pragma unroll
      for (int t = 0; t < 4; ++t)
        Pf[w][(lh*4 + rr)*68 + lg + 16*t] = p[rr][t] * vsv[t];

    // --- rescale O accumulators ---
    #pragma unroll
    for (int dt = 0; dt < 8; ++dt)
      #pragma unroll
      for (int rr = 0; rr < 4; ++rr) acc_o[dt][rr] *= corr[rr];

    // --- build split-bf16 A-frags from P' ---
    s16x8 pahi[2], palo[2];
    #pragma unroll
    for (int kb = 0; kb < 2; ++kb) {
      const float* pr = &Pf[w][lg*68 + kb*32 + lh*8];
      f32x4 x0 = *(const f32x4*)pr;
      f32x4 x1 = *(const f32x4*)(pr + 4);
      float xv[8] = {x0.x, x0.y, x0.z, x0.w, x1.x, x1.y, x1.z, x1.w};
      float lv[8];
      #pragma unroll
      for (int j = 0; j < 8; ++j) {
        uint32_t hb = fbits(xv[j]) & 0xffff0000u;
        union { uint32_t u; float f; } hf; hf.u = hb;
        lv[j] = xv[j] - hf.f;
      }
      union { uint32_t u[4]; s16x8 v; } H, L;
      #pragma unroll
      for (int jj = 0; jj < 4; ++jj) {
        H.u[jj] = (fbits(xv[2*jj]) >> 16) | (fbits(xv[2*jj+1]) & 0xffff0000u);
        L.u[jj] = (fbits(lv[2*jj]) >> 16) | (fbits(lv[2*jj+1]) & 0xffff0000u);
      }
      pahi[kb] = H.v; palo[kb] = L.v;
    }

    // --- PV MFMAs ---
    #pragma unroll
    for (int dt = 0; dt < 8; ++dt) {
      #pragma unroll
      for (int kb = 0; kb < 2; ++kb) {
        s16x8 vb = *(const s16x8*)&Vt[(lg + 16*dt)*72 + kb*32 + lh*8];
        acc_o[dt] = mfma_bf16(pahi[kb], vb, acc_o[dt]);
        acc_o[dt] = mfma_bf16(palo[kb], vb, acc_o[dt]);
      }
    }
  }

  // epilogue: divide by l and store (rows lh*4+rr, cols lg+16*dt)
  float inv[4];
  #pragma unroll
  for (int rr = 0; rr < 4; ++rr) inv[rr] = 1.0f / lrun[rr];
  #pragma unroll
  for (int dt = 0; dt < 8; ++dt)
    #pragma unroll
    for (int rr = 0; rr < 4; ++rr)
      ao[(size_t)(qb0 + 16*w + lh*4 + rr)*DD + (size_t)h*HD + 16*dt + lg] =
          acc_o[dt][rr] * inv[rr];
}

// ---------------------------------------------------------------------------
// Kernel 4: f32 output projection.
// ---------------------------------------------------------------------------
__global__ __launch_bounds__(256)
void wo_gemm_kernel(const float* __restrict__ ao, const float* __restrict__ wom,
                    float* __restrict__ outp) {
  int o0 = blockIdx.x * 128;
  int t0 = blockIdx.y * 64;
  __shared__ float As[32][68];
  __shared__ float Bs[32][132];
  int tid = threadIdx.x;
  int tg = tid >> 4;
  int og = tid & 15;
  float acc[4][8];
  #pragma unroll
  for (int i = 0; i < 4; ++i)
    #pragma unroll
    for (int j = 0; j < 8; ++j) acc[i][j] = 0.0f;

  for (int kt = 0; kt < 64; ++kt) {
    int k0 = kt * 32;
    #pragma unroll
    for (int i = 0; i < 2; ++i) {
      int idx = tid + i*256, r = idx >> 3, c4 = (idx & 7)*4;
      float4 a = *(const float4*)&ao[(size_t)(t0 + r)*DD + k0 + c4];
      As[c4+0][r] = a.x; As[c4+1][r] = a.y; As[c4+2][r] = a.z; As[c4+3][r] = a.w;
    }
    #pragma unroll
    for (int i = 0; i < 4; ++i) {
      int idx = tid + i*256, r = idx >> 3, c4 = (idx & 7)*4;
      float4 b = *(const float4*)&wom[(size_t)(o0 + r)*DD + k0 + c4];
      Bs[c4+0][r] = b.x; Bs[c4+1][r] = b.y; Bs[c4+2][r] = b.z; Bs[c4+3][r] = b.w;
    }
    __syncthreads();
    #pragma unroll 8
    for (int kk = 0; kk < 32; ++kk) {
      float4 a  = *(const float4*)&As[kk][tg*4];
      float4 b0 = *(const float4*)&Bs[kk][og*8];
      float4 b1 = *(const float4*)&Bs[kk][og*8 + 4];
      float av[4] = {a.x, a.y, a.z, a.w};
      float bv[8] = {b0.x, b0.y, b0.z, b0.w, b1.x, b1.y, b1.z, b1.w};
      #pragma unroll
      for (int i = 0; i < 4; ++i)
        #pragma unroll
        for (int j = 0; j < 8; ++j)
          acc[i][j] = fmaf(av[i], bv[j], acc[i][j]);
    }
    __syncthreads();
  }
  #pragma unroll
  for (int i = 0; i < 4; ++i) {
    size_t ob = (size_t)(t0 + tg*4 + i)*DD + o0 + og*8;
    *(float4*)&outp[ob]     = make_float4(acc[i][0], acc[i][1], acc[i][2], acc[i][3]);
    *(float4*)&outp[ob + 4] = make_float4(acc[i][4], acc[i][5], acc[i][6], acc[i][7]);
  }
}

// ---------------------------------------------------------------------------
extern "C" void kernel_launch(void* const* d_in, const int* in_sizes, int n_in,
                              void* d_out, int out_size, void* d_ws, size_t ws_size,
                              hipStream_t stream) {
  (void)in_sizes; (void)n_in; (void)out_size; (void)ws_size;
  const float* x  = (const float*)d_in[0];
  const float* wq = (const float*)d_in[1];
  const float* wk = (const float*)d_in[2];
  const float* wv = (const float*)d_in[3];
  const float* wo = (const float*)d_in[4];
  float* out = (float*)d_out;

  char* ws = (char*)d_ws;
  const size_t MB = 1024*1024;
  int8_t* qx  = (int8_t*)(ws);           // [2048][2048]; dead after proj_kernel
  int8_t* qwq = (int8_t*)(ws + 4*MB);
  int8_t* qwk = (int8_t*)(ws + 8*MB);
  int8_t* qwv = (int8_t*)(ws + 9*MB);
  int8_t* qqp = (int8_t*)(ws + 10*MB);   // [16][2048][128]
  int8_t* kqp = (int8_t*)(ws + 14*MB);   // [4][2048][128]
  int8_t* vqp = (int8_t*)(ws + 15*MB);   // [4][2048][128]
  float* fb  = (float*)(ws + 16*MB);
  float* xs  = fb;
  float* wqs = xs + 2048;
  float* wks = wqs + 2048;
  float* wvs = wks + 512;
  float* qsc = wvs + 512;
  float* ksc = qsc + (size_t)NH*TT;
  float* vsc = ksc + (size_t)NKV*TT;
  float* ao  = vsc + (size_t)NKV*TT;     // 2048*2048 f32
  // vbf reuses the qx region (qx dead once proj_kernel completes; kernels
  // on `stream` serialize) -> peak ws usage stays ~32.3 MB.
  ushort* vbf = (ushort*)(ws);           // [4][2048][128] bf16, 2 MB

  quant_rows_kernel<<<5120, 256, 0, stream>>>(x, wq, wk, wv,
                                              qx, xs, qwq, wqs, qwk, wks, qwv, wvs);
  proj_kernel<<<dim3(TT/128, NH + 2*NKV), 256, 0, stream>>>(
      qx, xs, qwq, wqs, qwk, wks, qwv, wvs,
      qqp, qsc, kqp, ksc, vqp, vsc);
  vcvt_kernel<<<512, 256, 0, stream>>>(vqp, vbf);
  attn_mfma_kernel<<<dim3(TT/64, NH), 256, 0, stream>>>(
      qqp, qsc, kqp, ksc, vbf, vsc, ao);
  wo_gemm_kernel<<<dim3(DD/128, TT/64), 256, 0, stream>>>(ao, wo, out);
}

// Round 4
// 313.875 us; speedup vs baseline: 2.9286x; 2.0281x over previous
//
#include <hip/hip_runtime.h>
#include <cstdint>
#include <math.h>

#define TT 2048
#define DD 2048
#define NH 16
#define NKV 4
#define HD 128
#define SCALE_F 0.08838834764831845f
#define LOG2E 1.4426950408889634f

typedef int   i32x4 __attribute__((ext_vector_type(4)));
typedef float f32x4 __attribute__((ext_vector_type(4)));
typedef short s16x8 __attribute__((ext_vector_type(8)));

__device__ __forceinline__ i32x4 mfma_i8(i32x4 a, i32x4 b, i32x4 c) {
  return __builtin_amdgcn_mfma_i32_16x16x64_i8(a, b, c, 0, 0, 0);
}
__device__ __forceinline__ f32x4 mfma_bf16(s16x8 a, s16x8 b, f32x4 c) {
  return __builtin_amdgcn_mfma_f32_16x16x32_bf16(a, b, c, 0, 0, 0);
}
__device__ __forceinline__ uint32_t fbits(float f) {
  union { float f; uint32_t u; } x; x.f = f; return x.u;
}
__device__ __forceinline__ ushort bf16_rne(float v) {
  uint32_t u = fbits(v);
  return (ushort)((u + 0x7fffu + ((u >> 16) & 1u)) >> 16);
}
__device__ __forceinline__ float bf16_to_f(ushort h) {
  union { uint32_t u; float f; } x; x.u = ((uint32_t)h) << 16; return x.f;
}

// ---------------------------------------------------------------------------
// Kernel 1: rowwise symmetric int8 quantization for x, wq, wk, wv.
// ---------------------------------------------------------------------------
__global__ __launch_bounds__(256)
void quant_rows_kernel(const float* __restrict__ x, const float* __restrict__ wq,
                       const float* __restrict__ wk, const float* __restrict__ wv,
                       int8_t* __restrict__ qx, float* __restrict__ xs,
                       int8_t* __restrict__ qwq, float* __restrict__ wqs,
                       int8_t* __restrict__ qwk, float* __restrict__ wks,
                       int8_t* __restrict__ qwv, float* __restrict__ wvs) {
  int r = blockIdx.x;
  const float* src; int8_t* dst; float* sc; int row;
  if (r < 2048)      { src = x;  dst = qx;  sc = xs;  row = r; }
  else if (r < 4096) { src = wq; dst = qwq; sc = wqs; row = r - 2048; }
  else if (r < 4608) { src = wk; dst = qwk; sc = wks; row = r - 4096; }
  else               { src = wv; dst = qwv; sc = wvs; row = r - 4608; }
  src += (size_t)row * DD; dst += (size_t)row * DD;
  int tid = threadIdx.x;
  float4 v0 = ((const float4*)src)[2*tid];
  float4 v1 = ((const float4*)src)[2*tid+1];
  float m = fmaxf(fmaxf(fmaxf(fabsf(v0.x), fabsf(v0.y)), fmaxf(fabsf(v0.z), fabsf(v0.w))),
                  fmaxf(fmaxf(fabsf(v1.x), fabsf(v1.y)), fmaxf(fabsf(v1.z), fabsf(v1.w))));
  #pragma unroll
  for (int off = 1; off < 64; off <<= 1) m = fmaxf(m, __shfl_xor(m, off));
  __shared__ float wmax[4];
  if ((tid & 63) == 0) wmax[tid >> 6] = m;
  __syncthreads();
  m = fmaxf(fmaxf(wmax[0], wmax[1]), fmaxf(wmax[2], wmax[3]));
  float s = fmaxf(m / 127.0f, 1e-8f);
  if (tid == 0) sc[row] = s;
  float vv[8] = {v0.x, v0.y, v0.z, v0.w, v1.x, v1.y, v1.z, v1.w};
  uint32_t p0 = 0, p1 = 0;
  #pragma unroll
  for (int i = 0; i < 4; ++i) {
    int q = (int)fminf(fmaxf(rintf(vv[i] / s), -127.0f), 127.0f);
    p0 |= ((uint32_t)q & 0xffu) << (8*i);
  }
  #pragma unroll
  for (int i = 0; i < 4; ++i) {
    int q = (int)fminf(fmaxf(rintf(vv[4+i] / s), -127.0f), 127.0f);
    p1 |= ((uint32_t)q & 0xffu) << (8*i);
  }
  ((uint2*)dst)[tid] = make_uint2(p0, p1);
}

// ---------------------------------------------------------------------------
// Kernel 2: i8-MFMA projection GEMM + dequant + RoPE + rowwise requant.
// Tile 128t x 128o, BK=128 bytes. 4 waves split along t (32 rows each, full
// 128 o-cols per wave) so RoPE pairs (d, d+64) and row-max stay lane-local.
// MFMA C layout: t-row = (lane>>4)*4 + reg, o-col = lane&15 (+16*tj).
// ---------------------------------------------------------------------------
__global__ __launch_bounds__(256)
void proj_kernel(const int8_t* __restrict__ qx, const float* __restrict__ xs,
                 const int8_t* __restrict__ qwq, const float* __restrict__ wqs,
                 const int8_t* __restrict__ qwk, const float* __restrict__ wks,
                 const int8_t* __restrict__ qwv, const float* __restrict__ wvs,
                 int8_t* __restrict__ qq, float* __restrict__ qsc_out,
                 int8_t* __restrict__ kq, float* __restrict__ ksc_out,
                 int8_t* __restrict__ vq, float* __restrict__ vsc_out) {
  int gh = blockIdx.y;
  int t0 = blockIdx.x * 128;
  const int8_t* w; const float* wsc; int8_t* outq; float* outs; bool doRope;
  if (gh < NH) {
    w = qwq + (size_t)gh*HD*DD; wsc = wqs + gh*HD;
    outq = qq + (size_t)gh*TT*HD; outs = qsc_out + (size_t)gh*TT; doRope = true;
  } else if (gh < NH + NKV) {
    int hh = gh - NH;
    w = qwk + (size_t)hh*HD*DD; wsc = wks + hh*HD;
    outq = kq + (size_t)hh*TT*HD; outs = ksc_out + (size_t)hh*TT; doRope = true;
  } else {
    int hh = gh - NH - NKV;
    w = qwv + (size_t)hh*HD*DD; wsc = wvs + hh*HD;
    outq = vq + (size_t)hh*TT*HD; outs = vsc_out + (size_t)hh*TT; doRope = false;
  }

  __shared__ int8_t As[128 * 144];   // [t][k] int8, 144B row stride
  __shared__ int8_t Bs[128 * 144];   // [o][k]
  int tid = threadIdx.x;
  int wv4 = tid >> 6;   // wave: t rows wv4*32 .. +31
  int l  = tid & 63;
  int lg = l & 15;
  int lh = l >> 4;

  i32x4 acc[2][8];
  #pragma unroll
  for (int ti = 0; ti < 2; ++ti)
    #pragma unroll
    for (int tj = 0; tj < 8; ++tj) acc[ti][tj] = (i32x4){0,0,0,0};

  for (int kt = 0; kt < DD/128; ++kt) {
    int k0 = kt * 128;
    __syncthreads();
    #pragma unroll
    for (int i = 0; i < 4; ++i) {
      int idx = tid + i*256, r = idx >> 3, c = idx & 7;
      *(i32x4*)&As[r*144 + c*16] = *(const i32x4*)&qx[(size_t)(t0 + r)*DD + k0 + c*16];
      *(i32x4*)&Bs[r*144 + c*16] = *(const i32x4*)&w[(size_t)r*DD + k0 + c*16];
    }
    __syncthreads();
    #pragma unroll
    for (int s = 0; s < 2; ++s) {
      i32x4 a0 = *(const i32x4*)&As[(wv4*32 + lg)*144      + s*64 + lh*16];
      i32x4 a1 = *(const i32x4*)&As[(wv4*32 + 16 + lg)*144 + s*64 + lh*16];
      #pragma unroll
      for (int tj = 0; tj < 8; ++tj) {
        i32x4 b = *(const i32x4*)&Bs[(tj*16 + lg)*144 + s*64 + lh*16];
        acc[0][tj] = mfma_i8(a0, b, acc[0][tj]);
        acc[1][tj] = mfma_i8(a1, b, acc[1][tj]);
      }
    }
  }

  // ---- epilogue: dequant -> RoPE -> rowwise requant ----
  float y[2][8][4];
  #pragma unroll
  for (int ti = 0; ti < 2; ++ti)
    #pragma unroll
    for (int rr = 0; rr < 4; ++rr) {
      int tl = wv4*32 + ti*16 + lh*4 + rr;
      float xsi = xs[t0 + tl];
      #pragma unroll
      for (int tj = 0; tj < 8; ++tj)
        y[ti][tj][rr] = (float)acc[ti][tj][rr] * xsi * wsc[tj*16 + lg];
    }

  if (doRope) {
    float invf[4];
    #pragma unroll
    for (int tj = 0; tj < 4; ++tj)
      invf[tj] = 1.0f / powf(1000000.0f, (float)(tj*16 + lg) * (1.0f/64.0f));
    #pragma unroll
    for (int ti = 0; ti < 2; ++ti)
      #pragma unroll
      for (int rr = 0; rr < 4; ++rr) {
        float trow = (float)(t0 + wv4*32 + ti*16 + lh*4 + rr);
        #pragma unroll
        for (int tj = 0; tj < 4; ++tj) {
          float sn, cs;
          sincosf(trow * invf[tj], &sn, &cs);
          float lo = y[ti][tj][rr], hi = y[ti][tj+4][rr];
          y[ti][tj][rr]   = lo*cs - hi*sn;
          y[ti][tj+4][rr] = hi*cs + lo*sn;
        }
      }
  }

  __syncthreads();   // done with As/Bs as GEMM tiles; reuse As for output
  #pragma unroll
  for (int ti = 0; ti < 2; ++ti)
    #pragma unroll
    for (int rr = 0; rr < 4; ++rr) {
      int tl = wv4*32 + ti*16 + lh*4 + rr;
      float mx = fabsf(y[ti][0][rr]);
      #pragma unroll
      for (int tj = 1; tj < 8; ++tj) mx = fmaxf(mx, fabsf(y[ti][tj][rr]));
      mx = fmaxf(mx, __shfl_xor(mx, 1));
      mx = fmaxf(mx, __shfl_xor(mx, 2));
      mx = fmaxf(mx, __shfl_xor(mx, 4));
      mx = fmaxf(mx, __shfl_xor(mx, 8));
      float s = fmaxf(mx / 127.0f, 1e-8f);
      if (lg == 0) outs[t0 + tl] = s;
      #pragma unroll
      for (int tj = 0; tj < 8; ++tj) {
        int qv = (int)fminf(fmaxf(rintf(y[ti][tj][rr] / s), -127.0f), 127.0f);
        As[tl*144 + tj*16 + lg] = (int8_t)qv;
      }
    }
  __syncthreads();
  #pragma unroll
  for (int i = 0; i < 4; ++i) {
    int idx = tid + i*256, r = idx >> 3, c = idx & 7;
    *(i32x4*)&outq[(size_t)(t0 + r)*HD + c*16] = *(const i32x4*)&As[r*144 + c*16];
  }
}

// ---------------------------------------------------------------------------
// Kernel 2b: convert int8 V to bf16 (exact: |v|<=127 fits bf16 mantissa).
// ---------------------------------------------------------------------------
__global__ __launch_bounds__(256)
void vcvt_kernel(const int8_t* __restrict__ vq, ushort* __restrict__ vbf) {
  int idx = blockIdx.x * 256 + threadIdx.x;     // 0..131071
  int2 raw = ((const int2*)vq)[idx];
  s16x8 pack;
  #pragma unroll
  for (int j = 0; j < 4; ++j) {
    int v0 = (raw.x << (24 - 8*j)) >> 24;
    int v1 = (raw.y << (24 - 8*j)) >> 24;
    pack[j]     = (short)(fbits((float)v0) >> 16);
    pack[4 + j] = (short)(fbits((float)v1) >> 16);
  }
  ((s16x8*)vbf)[idx] = pack;
}

// ---------------------------------------------------------------------------
// Kernel 3: MFMA flash attention (scores i8-exact, PV split-bf16).
// Epilogue now emits ao as split hi/lo bf16 for the MFMA wo GEMM.
// ---------------------------------------------------------------------------
__global__ __launch_bounds__(256)
void attn_mfma_kernel(const int8_t* __restrict__ qq, const float* __restrict__ qsc_in,
                      const int8_t* __restrict__ kq, const float* __restrict__ ksc_in,
                      const ushort* __restrict__ vbf, const float* __restrict__ vsc_in,
                      ushort* __restrict__ aoh, ushort* __restrict__ aol) {
  int h = blockIdx.y;
  int qbIdx = (int)gridDim.x - 1 - (int)blockIdx.x;   // longest blocks first
  int hk = h >> 2;
  int qb0 = qbIdx * 64;
  int nkt = qbIdx + 1;

  __shared__ int8_t Ks[64 * 144];
  __shared__ ushort Vt[128 * 72];
  __shared__ float  Pf[4][16 * 68];

  int tid = threadIdx.x;
  int w  = tid >> 6;
  int l  = tid & 63;
  int lg = l & 15;
  int lh = l >> 4;

  const int8_t* qp = &qq[((size_t)h*TT + qb0 + 16*w + lg)*HD + lh*16];
  i32x4 qa0 = *(const i32x4*)qp;
  i32x4 qa1 = *(const i32x4*)(qp + 64);

  float qsl[4];
  #pragma unroll
  for (int rr = 0; rr < 4; ++rr)
    qsl[rr] = qsc_in[(size_t)h*TT + qb0 + 16*w + lh*4 + rr] * (SCALE_F * LOG2E);

  float mrun[4] = {-1e30f, -1e30f, -1e30f, -1e30f};
  float lrun[4] = {0.f, 0.f, 0.f, 0.f};
  f32x4 acc_o[8];
  #pragma unroll
  for (int dt = 0; dt < 8; ++dt) acc_o[dt] = (f32x4){0.f, 0.f, 0.f, 0.f};

  for (int kt = 0; kt < nkt; ++kt) {
    int k0 = kt * 64;
    __syncthreads();
    #pragma unroll
    for (int i = 0; i < 2; ++i) {
      int idx = tid + i*256, r = idx >> 3, c = idx & 7;
      *(i32x4*)&Ks[r*144 + c*16] =
          *(const i32x4*)&kq[((size_t)hk*TT + k0 + r)*HD + c*16];
    }
    #pragma unroll
    for (int it = 0; it < 2; ++it) {
      int a = tid + it*256;
      int m2 = a & 31, d0 = (a >> 5) * 8;
      const ushort* vp = &vbf[((size_t)hk*TT + k0 + 2*m2)*HD + d0];
      s16x8 r0 = *(const s16x8*)vp;
      s16x8 r1 = *(const s16x8*)(vp + HD);
      #pragma unroll
      for (int j = 0; j < 8; ++j) {
        uint32_t pk = (uint32_t)(uint16_t)r0[j] | ((uint32_t)(uint16_t)r1[j] << 16);
        *(uint32_t*)&Vt[(d0 + j)*72 + 2*m2] = pk;
      }
    }
    __syncthreads();

    i32x4 sacc[4];
    #pragma unroll
    for (int t = 0; t < 4; ++t) sacc[t] = (i32x4){0, 0, 0, 0};
    #pragma unroll
    for (int t = 0; t < 4; ++t) {
      const int8_t* kp = &Ks[(lg + 16*t)*144 + lh*16];
      i32x4 b0 = *(const i32x4*)kp;
      i32x4 b1 = *(const i32x4*)(kp + 64);
      sacc[t] = mfma_i8(qa0, b0, sacc[t]);
      sacc[t] = mfma_i8(qa1, b1, sacc[t]);
    }

    float ksv[4], vsv[4];
    #pragma unroll
    for (int t = 0; t < 4; ++t) {
      ksv[t] = ksc_in[(size_t)hk*TT + k0 + lg + 16*t];
      vsv[t] = vsc_in[(size_t)hk*TT + k0 + lg + 16*t];
    }

    bool maskTile = (kt == nkt - 1);
    float sf[4][4];
    #pragma unroll
    for (int t = 0; t < 4; ++t)
      #pragma unroll
      for (int rr = 0; rr < 4; ++rr) {
        float v = (float)sacc[t][rr] * qsl[rr] * ksv[t];
        if (maskTile) {
          int kkg = k0 + lg + 16*t;
          int qrow = qb0 + 16*w + lh*4 + rr;
          v = (kkg <= qrow) ? v : -1e30f;
        }
        sf[rr][t] = v;
      }

    float corr[4], p[4][4];
    #pragma unroll
    for (int rr = 0; rr < 4; ++rr) {
      float rm = fmaxf(fmaxf(sf[rr][0], sf[rr][1]), fmaxf(sf[rr][2], sf[rr][3]));
      rm = fmaxf(rm, __shfl_xor(rm, 1));
      rm = fmaxf(rm, __shfl_xor(rm, 2));
      rm = fmaxf(rm, __shfl_xor(rm, 4));
      rm = fmaxf(rm, __shfl_xor(rm, 8));
      float mnew = fmaxf(mrun[rr], rm);
      corr[rr] = exp2f(mrun[rr] - mnew);
      mrun[rr] = mnew;
      float ps = 0.f;
      #pragma unroll
      for (int t = 0; t < 4; ++t) { p[rr][t] = exp2f(sf[rr][t] - mnew); ps += p[rr][t]; }
      ps += __shfl_xor(ps, 1);
      ps += __shfl_xor(ps, 2);
      ps += __shfl_xor(ps, 4);
      ps += __shfl_xor(ps, 8);
      lrun[rr] = lrun[rr]*corr[rr] + ps;
    }

    #pragma unroll
    for (int rr = 0; rr < 4; ++rr)
      #pragma unroll
      for (int t = 0; t < 4; ++t)
        Pf[w][(lh*4 + rr)*68 + lg + 16*t] = p[rr][t] * vsv[t];

    #pragma unroll
    for (int dt = 0; dt < 8; ++dt)
      #pragma unroll
      for (int rr = 0; rr < 4; ++rr) acc_o[dt][rr] *= corr[rr];

    s16x8 pahi[2], palo[2];
    #pragma unroll
    for (int kb = 0; kb < 2; ++kb) {
      const float* pr = &Pf[w][lg*68 + kb*32 + lh*8];
      f32x4 x0 = *(const f32x4*)pr;
      f32x4 x1 = *(const f32x4*)(pr + 4);
      float xv[8] = {x0.x, x0.y, x0.z, x0.w, x1.x, x1.y, x1.z, x1.w};
      float lv[8];
      #pragma unroll
      for (int j = 0; j < 8; ++j) {
        uint32_t hb = fbits(xv[j]) & 0xffff0000u;
        union { uint32_t u; float f; } hf; hf.u = hb;
        lv[j] = xv[j] - hf.f;
      }
      union { uint32_t u[4]; s16x8 v; } H, L;
      #pragma unroll
      for (int jj = 0; jj < 4; ++jj) {
        H.u[jj] = (fbits(xv[2*jj]) >> 16) | (fbits(xv[2*jj+1]) & 0xffff0000u);
        L.u[jj] = (fbits(lv[2*jj]) >> 16) | (fbits(lv[2*jj+1]) & 0xffff0000u);
      }
      pahi[kb] = H.v; palo[kb] = L.v;
    }

    #pragma unroll
    for (int dt = 0; dt < 8; ++dt) {
      #pragma unroll
      for (int kb = 0; kb < 2; ++kb) {
        s16x8 vb = *(const s16x8*)&Vt[(lg + 16*dt)*72 + kb*32 + lh*8];
        acc_o[dt] = mfma_bf16(pahi[kb], vb, acc_o[dt]);
        acc_o[dt] = mfma_bf16(palo[kb], vb, acc_o[dt]);
      }
    }
  }

  // epilogue: divide by l, split into hi/lo bf16, store
  float inv[4];
  #pragma unroll
  for (int rr = 0; rr < 4; ++rr) inv[rr] = 1.0f / lrun[rr];
  #pragma unroll
  for (int dt = 0; dt < 8; ++dt)
    #pragma unroll
    for (int rr = 0; rr < 4; ++rr) {
      float v = acc_o[dt][rr] * inv[rr];
      ushort hb = bf16_rne(v);
      float lo = v - bf16_to_f(hb);
      ushort lb = bf16_rne(lo);
      size_t idx = (size_t)(qb0 + 16*w + lh*4 + rr)*DD + (size_t)h*HD + 16*dt + lg;
      aoh[idx] = hb;
      aol[idx] = lb;
    }
}

// ---------------------------------------------------------------------------
// Kernel 3b: split wo (f32) into hi/lo bf16.
// ---------------------------------------------------------------------------
__global__ __launch_bounds__(256)
void wcvt_kernel(const float* __restrict__ wom, ushort* __restrict__ woh,
                 ushort* __restrict__ wol) {
  size_t base = ((size_t)blockIdx.x * 256 + threadIdx.x) * 8;
  float4 a = *(const float4*)&wom[base];
  float4 b = *(const float4*)&wom[base + 4];
  float vv[8] = {a.x, a.y, a.z, a.w, b.x, b.y, b.z, b.w};
  s16x8 H, L;
  #pragma unroll
  for (int j = 0; j < 8; ++j) {
    ushort hb = bf16_rne(vv[j]);
    float lo = vv[j] - bf16_to_f(hb);
    H[j] = (short)hb;
    L[j] = (short)bf16_rne(lo);
  }
  *(s16x8*)&woh[base] = H;
  *(s16x8*)&wol[base] = L;
}

// ---------------------------------------------------------------------------
// Kernel 4: wo GEMM on bf16 MFMA with 3-product split (~f32 precision).
// out[t,o] = sum_d ao[t,d]*wo[o,d]. Tile 128x128, BK=64, 2x2 wave split.
// ---------------------------------------------------------------------------
__global__ __launch_bounds__(256)
void wo_gemm_kernel(const ushort* __restrict__ aoh, const ushort* __restrict__ aol,
                    const ushort* __restrict__ woh, const ushort* __restrict__ wol,
                    float* __restrict__ outp) {
  int o0 = blockIdx.x * 128;
  int t0 = blockIdx.y * 128;
  __shared__ ushort AH[128 * 72];
  __shared__ ushort AL[128 * 72];
  __shared__ ushort BH[128 * 72];
  __shared__ ushort BL[128 * 72];
  int tid = threadIdx.x;
  int wv4 = tid >> 6;
  int wr = wv4 >> 1, wc = wv4 & 1;    // wave tile: 64t x 64o
  int l  = tid & 63;
  int lg = l & 15;
  int lh = l >> 4;

  f32x4 acc[4][4];
  #pragma unroll
  for (int ti = 0; ti < 4; ++ti)
    #pragma unroll
    for (int tj = 0; tj < 4; ++tj) acc[ti][tj] = (f32x4){0.f,0.f,0.f,0.f};

  for (int kt = 0; kt < DD/64; ++kt) {
    int k0 = kt * 64;
    __syncthreads();
    #pragma unroll
    for (int i = 0; i < 4; ++i) {
      int idx = tid + i*256, r = idx >> 3, c = idx & 7;
      size_t ga = (size_t)(t0 + r)*DD + k0 + c*8;
      size_t gb = (size_t)(o0 + r)*DD + k0 + c*8;
      *(s16x8*)&AH[r*72 + c*8] = *(const s16x8*)&aoh[ga];
      *(s16x8*)&AL[r*72 + c*8] = *(const s16x8*)&aol[ga];
      *(s16x8*)&BH[r*72 + c*8] = *(const s16x8*)&woh[gb];
      *(s16x8*)&BL[r*72 + c*8] = *(const s16x8*)&wol[gb];
    }
    __syncthreads();
    #pragma unroll
    for (int s = 0; s < 2; ++s) {
      s16x8 ah[4], al[4];
      #pragma unroll
      for (int ti = 0; ti < 4; ++ti) {
        int ab = (wr*64 + ti*16 + lg)*72 + s*32 + lh*8;
        ah[ti] = *(const s16x8*)&AH[ab];
        al[ti] = *(const s16x8*)&AL[ab];
      }
      #pragma unroll
      for (int tj = 0; tj < 4; ++tj) {
        int bb = (wc*64 + tj*16 + lg)*72 + s*32 + lh*8;
        s16x8 bh = *(const s16x8*)&BH[bb];
        s16x8 bl = *(const s16x8*)&BL[bb];
        #pragma unroll
        for (int ti = 0; ti < 4; ++ti) {
          acc[ti][tj] = mfma_bf16(ah[ti], bh, acc[ti][tj]);
          acc[ti][tj] = mfma_bf16(ah[ti], bl, acc[ti][tj]);
          acc[ti][tj] = mfma_bf16(al[ti], bh, acc[ti][tj]);
        }
      }
    }
  }

  #pragma unroll
  for (int ti = 0; ti < 4; ++ti)
    #pragma unroll
    for (int tj = 0; tj < 4; ++tj)
      #pragma unroll
      for (int rr = 0; rr < 4; ++rr) {
        int t = t0 + wr*64 + ti*16 + lh*4 + rr;
        int o = o0 + wc*64 + tj*16 + lg;
        outp[(size_t)t*DD + o] = acc[ti][tj][rr];
      }
}

// ---------------------------------------------------------------------------
extern "C" void kernel_launch(void* const* d_in, const int* in_sizes, int n_in,
                              void* d_out, int out_size, void* d_ws, size_t ws_size,
                              hipStream_t stream) {
  (void)in_sizes; (void)n_in; (void)out_size; (void)ws_size;
  const float* x  = (const float*)d_in[0];
  const float* wq = (const float*)d_in[1];
  const float* wk = (const float*)d_in[2];
  const float* wv = (const float*)d_in[3];
  const float* wo = (const float*)d_in[4];
  float* out = (float*)d_out;

  char* ws = (char*)d_ws;
  const size_t MB = 1048576;
  int8_t* qx  = (int8_t*)(ws);           // dead after proj
  int8_t* qwq = (int8_t*)(ws + 4*MB);    // dead after proj
  int8_t* qwk = (int8_t*)(ws + 8*MB);    // dead after proj
  int8_t* qwv = (int8_t*)(ws + 9*MB);    // dead after proj
  int8_t* qqp = (int8_t*)(ws + 10*MB);   // [16][2048][128]; dead after attn
  int8_t* kqp = (int8_t*)(ws + 14*MB);   // [4][2048][128]; dead after attn
  int8_t* vqp = (int8_t*)(ws + 15*MB);   // [4][2048][128]; dead after vcvt
  float* xs  = (float*)(ws + 16*MB);
  float* wqs = xs + 2048;
  float* wks = wqs + 2048;
  float* wvs = wks + 512;
  float* qsc = wvs + 512;
  float* ksc = qsc + (size_t)NH*TT;
  float* vsc = ksc + (size_t)NKV*TT;
  ushort* aoh = (ushort*)(ws + 16*MB + 262144);   // 8 MB
  ushort* aol = (ushort*)(ws + 24*MB + 262144);   // 8 MB
  // vbf overlaps qx (written after proj, read by attn)
  ushort* vbf = (ushort*)(ws);                    // 2 MB
  // woh/wol overlap bytes 0..16MB (written after attn, when all dead)
  ushort* woh = (ushort*)(ws);                    // 8 MB
  ushort* wol = (ushort*)(ws + 8*MB);             // 8 MB

  quant_rows_kernel<<<5120, 256, 0, stream>>>(x, wq, wk, wv,
                                              qx, xs, qwq, wqs, qwk, wks, qwv, wvs);
  proj_kernel<<<dim3(TT/128, NH + 2*NKV), 256, 0, stream>>>(
      qx, xs, qwq, wqs, qwk, wks, qwv, wvs,
      qqp, qsc, kqp, ksc, vqp, vsc);
  vcvt_kernel<<<512, 256, 0, stream>>>(vqp, vbf);
  attn_mfma_kernel<<<dim3(TT/64, NH), 256, 0, stream>>>(
      qqp, qsc, kqp, ksc, vbf, vsc, aoh, aol);
  wcvt_kernel<<<2048, 256, 0, stream>>>(wo, woh, wol);
  wo_gemm_kernel<<<dim3(DD/128, TT/128), 256, 0, stream>>>(aoh, aol, woh, wol, out);
}

// Round 5
// 223.486 us; speedup vs baseline: 4.1131x; 1.4044x over previous
//
#include <hip/hip_runtime.h>
#include <cstdint>
#include <math.h>

#define TT 2048
#define DD 2048
#define NH 16
#define NKV 4
#define HD 128
#define SCALE_F 0.08838834764831845f
#define LOG2E 1.4426950408889634f

#if __has_builtin(__builtin_amdgcn_exp2f)
#define EXP2(x) __builtin_amdgcn_exp2f(x)
#else
#define EXP2(x) exp2f(x)
#endif

typedef int   i32x4 __attribute__((ext_vector_type(4)));
typedef float f32x4 __attribute__((ext_vector_type(4)));
typedef short s16x8 __attribute__((ext_vector_type(8)));

__device__ __forceinline__ i32x4 mfma_i8(i32x4 a, i32x4 b, i32x4 c) {
  return __builtin_amdgcn_mfma_i32_16x16x64_i8(a, b, c, 0, 0, 0);
}
__device__ __forceinline__ f32x4 mfma_bf16(s16x8 a, s16x8 b, f32x4 c) {
  return __builtin_amdgcn_mfma_f32_16x16x32_bf16(a, b, c, 0, 0, 0);
}
__device__ __forceinline__ uint32_t fbits(float f) {
  union { float f; uint32_t u; } x; x.f = f; return x.u;
}
__device__ __forceinline__ ushort bf16_rne(float v) {
  uint32_t u = fbits(v);
  return (ushort)((u + 0x7fffu + ((u >> 16) & 1u)) >> 16);
}
__device__ __forceinline__ float bf16_to_f(ushort h) {
  union { uint32_t u; float f; } x; x.u = ((uint32_t)h) << 16; return x.f;
}

// ---------------------------------------------------------------------------
// Kernel 1: rowwise symmetric int8 quantization for x, wq, wk, wv.
// ---------------------------------------------------------------------------
__global__ __launch_bounds__(256)
void quant_rows_kernel(const float* __restrict__ x, const float* __restrict__ wq,
                       const float* __restrict__ wk, const float* __restrict__ wv,
                       int8_t* __restrict__ qx, float* __restrict__ xs,
                       int8_t* __restrict__ qwq, float* __restrict__ wqs,
                       int8_t* __restrict__ qwk, float* __restrict__ wks,
                       int8_t* __restrict__ qwv, float* __restrict__ wvs) {
  int r = blockIdx.x;
  const float* src; int8_t* dst; float* sc; int row;
  if (r < 2048)      { src = x;  dst = qx;  sc = xs;  row = r; }
  else if (r < 4096) { src = wq; dst = qwq; sc = wqs; row = r - 2048; }
  else if (r < 4608) { src = wk; dst = qwk; sc = wks; row = r - 4096; }
  else               { src = wv; dst = qwv; sc = wvs; row = r - 4608; }
  src += (size_t)row * DD; dst += (size_t)row * DD;
  int tid = threadIdx.x;
  float4 v0 = ((const float4*)src)[2*tid];
  float4 v1 = ((const float4*)src)[2*tid+1];
  float m = fmaxf(fmaxf(fmaxf(fabsf(v0.x), fabsf(v0.y)), fmaxf(fabsf(v0.z), fabsf(v0.w))),
                  fmaxf(fmaxf(fabsf(v1.x), fabsf(v1.y)), fmaxf(fabsf(v1.z), fabsf(v1.w))));
  #pragma unroll
  for (int off = 1; off < 64; off <<= 1) m = fmaxf(m, __shfl_xor(m, off));
  __shared__ float wmax[4];
  if ((tid & 63) == 0) wmax[tid >> 6] = m;
  __syncthreads();
  m = fmaxf(fmaxf(wmax[0], wmax[1]), fmaxf(wmax[2], wmax[3]));
  float s = fmaxf(m / 127.0f, 1e-8f);
  if (tid == 0) sc[row] = s;
  float vv[8] = {v0.x, v0.y, v0.z, v0.w, v1.x, v1.y, v1.z, v1.w};
  uint32_t p0 = 0, p1 = 0;
  #pragma unroll
  for (int i = 0; i < 4; ++i) {
    int q = (int)fminf(fmaxf(rintf(vv[i] / s), -127.0f), 127.0f);
    p0 |= ((uint32_t)q & 0xffu) << (8*i);
  }
  #pragma unroll
  for (int i = 0; i < 4; ++i) {
    int q = (int)fminf(fmaxf(rintf(vv[4+i] / s), -127.0f), 127.0f);
    p1 |= ((uint32_t)q & 0xffu) << (8*i);
  }
  ((uint2*)dst)[tid] = make_uint2(p0, p1);
}

// ---------------------------------------------------------------------------
// Kernel 2: i8-MFMA projection GEMM + dequant + RoPE + rowwise requant.
// (unchanged from round 4 — verified)
// ---------------------------------------------------------------------------
__global__ __launch_bounds__(256)
void proj_kernel(const int8_t* __restrict__ qx, const float* __restrict__ xs,
                 const int8_t* __restrict__ qwq, const float* __restrict__ wqs,
                 const int8_t* __restrict__ qwk, const float* __restrict__ wks,
                 const int8_t* __restrict__ qwv, const float* __restrict__ wvs,
                 int8_t* __restrict__ qq, float* __restrict__ qsc_out,
                 int8_t* __restrict__ kq, float* __restrict__ ksc_out,
                 int8_t* __restrict__ vq, float* __restrict__ vsc_out) {
  int gh = blockIdx.y;
  int t0 = blockIdx.x * 128;
  const int8_t* w; const float* wsc; int8_t* outq; float* outs; bool doRope;
  if (gh < NH) {
    w = qwq + (size_t)gh*HD*DD; wsc = wqs + gh*HD;
    outq = qq + (size_t)gh*TT*HD; outs = qsc_out + (size_t)gh*TT; doRope = true;
  } else if (gh < NH + NKV) {
    int hh = gh - NH;
    w = qwk + (size_t)hh*HD*DD; wsc = wks + hh*HD;
    outq = kq + (size_t)hh*TT*HD; outs = ksc_out + (size_t)hh*TT; doRope = true;
  } else {
    int hh = gh - NH - NKV;
    w = qwv + (size_t)hh*HD*DD; wsc = wvs + hh*HD;
    outq = vq + (size_t)hh*TT*HD; outs = vsc_out + (size_t)hh*TT; doRope = false;
  }

  __shared__ int8_t As[128 * 144];
  __shared__ int8_t Bs[128 * 144];
  int tid = threadIdx.x;
  int wv4 = tid >> 6;
  int l  = tid & 63;
  int lg = l & 15;
  int lh = l >> 4;

  i32x4 acc[2][8];
  #pragma unroll
  for (int ti = 0; ti < 2; ++ti)
    #pragma unroll
    for (int tj = 0; tj < 8; ++tj) acc[ti][tj] = (i32x4){0,0,0,0};

  for (int kt = 0; kt < DD/128; ++kt) {
    int k0 = kt * 128;
    __syncthreads();
    #pragma unroll
    for (int i = 0; i < 4; ++i) {
      int idx = tid + i*256, r = idx >> 3, c = idx & 7;
      *(i32x4*)&As[r*144 + c*16] = *(const i32x4*)&qx[(size_t)(t0 + r)*DD + k0 + c*16];
      *(i32x4*)&Bs[r*144 + c*16] = *(const i32x4*)&w[(size_t)r*DD + k0 + c*16];
    }
    __syncthreads();
    #pragma unroll
    for (int s = 0; s < 2; ++s) {
      i32x4 a0 = *(const i32x4*)&As[(wv4*32 + lg)*144      + s*64 + lh*16];
      i32x4 a1 = *(const i32x4*)&As[(wv4*32 + 16 + lg)*144 + s*64 + lh*16];
      #pragma unroll
      for (int tj = 0; tj < 8; ++tj) {
        i32x4 b = *(const i32x4*)&Bs[(tj*16 + lg)*144 + s*64 + lh*16];
        acc[0][tj] = mfma_i8(a0, b, acc[0][tj]);
        acc[1][tj] = mfma_i8(a1, b, acc[1][tj]);
      }
    }
  }

  float y[2][8][4];
  #pragma unroll
  for (int ti = 0; ti < 2; ++ti)
    #pragma unroll
    for (int rr = 0; rr < 4; ++rr) {
      int tl = wv4*32 + ti*16 + lh*4 + rr;
      float xsi = xs[t0 + tl];
      #pragma unroll
      for (int tj = 0; tj < 8; ++tj)
        y[ti][tj][rr] = (float)acc[ti][tj][rr] * xsi * wsc[tj*16 + lg];
    }

  if (doRope) {
    float invf[4];
    #pragma unroll
    for (int tj = 0; tj < 4; ++tj)
      invf[tj] = 1.0f / powf(1000000.0f, (float)(tj*16 + lg) * (1.0f/64.0f));
    #pragma unroll
    for (int ti = 0; ti < 2; ++ti)
      #pragma unroll
      for (int rr = 0; rr < 4; ++rr) {
        float trow = (float)(t0 + wv4*32 + ti*16 + lh*4 + rr);
        #pragma unroll
        for (int tj = 0; tj < 4; ++tj) {
          float sn, cs;
          sincosf(trow * invf[tj], &sn, &cs);
          float lo = y[ti][tj][rr], hi = y[ti][tj+4][rr];
          y[ti][tj][rr]   = lo*cs - hi*sn;
          y[ti][tj+4][rr] = hi*cs + lo*sn;
        }
      }
  }

  __syncthreads();
  #pragma unroll
  for (int ti = 0; ti < 2; ++ti)
    #pragma unroll
    for (int rr = 0; rr < 4; ++rr) {
      int tl = wv4*32 + ti*16 + lh*4 + rr;
      float mx = fabsf(y[ti][0][rr]);
      #pragma unroll
      for (int tj = 1; tj < 8; ++tj) mx = fmaxf(mx, fabsf(y[ti][tj][rr]));
      mx = fmaxf(mx, __shfl_xor(mx, 1));
      mx = fmaxf(mx, __shfl_xor(mx, 2));
      mx = fmaxf(mx, __shfl_xor(mx, 4));
      mx = fmaxf(mx, __shfl_xor(mx, 8));
      float s = fmaxf(mx / 127.0f, 1e-8f);
      if (lg == 0) outs[t0 + tl] = s;
      #pragma unroll
      for (int tj = 0; tj < 8; ++tj) {
        int qv = (int)fminf(fmaxf(rintf(y[ti][tj][rr] / s), -127.0f), 127.0f);
        As[tl*144 + tj*16 + lg] = (int8_t)qv;
      }
    }
  __syncthreads();
  #pragma unroll
  for (int i = 0; i < 4; ++i) {
    int idx = tid + i*256, r = idx >> 3, c = idx & 7;
    *(i32x4*)&outq[(size_t)(t0 + r)*HD + c*16] = *(const i32x4*)&As[r*144 + c*16];
  }
}

// ---------------------------------------------------------------------------
// Kernel 3: MFMA flash attention, operand-swapped, K-split, reg-prefetch.
// Grid 768 linear: ids 0..511 = split halves of qb 16..31 (longest first);
// ids 512..767 = unsplit qb 15..0. 4 waves, QB=64 (16 q per wave), KB=64.
// Swapped QK^T (mfma(K,Q)) and swapped PV (mfma(V^T,P^T)): lane owns one
// q-column -> softmax needs only 2+2 shfl_xor; rescale/normalize lane-local.
// ---------------------------------------------------------------------------
__global__ __launch_bounds__(256)
void attn_mfma_kernel(const int8_t* __restrict__ qq, const float* __restrict__ qsc_in,
                      const int8_t* __restrict__ kq, const float* __restrict__ ksc_in,
                      const int8_t* __restrict__ vq, const float* __restrict__ vsc_in,
                      ushort* __restrict__ aoh, ushort* __restrict__ aol,
                      float* __restrict__ opart0, float* __restrict__ opart1,
                      float* __restrict__ mlm, float* __restrict__ mll) {
  int id = blockIdx.x;
  int h, qb, sp, ktb, kte;
  if (id < 512) {
    sp = id & 1;
    int r = id >> 1;
    h  = r & 15;
    qb = 31 - (r >> 4);
    int nkt = qb + 1, mid = nkt >> 1;
    ktb = sp ? mid : 0;
    kte = sp ? nkt : mid;
  } else {
    int r = id - 512;
    h  = r & 15;
    qb = 15 - (r >> 4);
    sp = -1;
    ktb = 0; kte = qb + 1;
  }
  int hk  = h >> 2;
  int qb0 = qb * 64;
  int nkt_full = qb + 1;

  __shared__ int8_t Ks[64 * 144];
  __shared__ ushort Vt[128 * 72];
  __shared__ float  Pf[4][16 * 68];

  int tid = threadIdx.x;
  int w  = tid >> 6;
  int l  = tid & 63;
  int lg = l & 15;
  int lh = l >> 4;

  // Q fragment (B operand of swapped QK^T): q-col = lg, d-bytes = lh*16 {+0,+64}
  const int8_t* qp = &qq[((size_t)h*TT + qb0 + 16*w + lg)*HD + lh*16];
  i32x4 qa0 = *(const i32x4*)qp;
  i32x4 qa1 = *(const i32x4*)(qp + 64);

  int myq = qb0 + 16*w + lg;                       // lane's q-row
  float qsl = qsc_in[(size_t)h*TT + myq] * (SCALE_F * LOG2E);

  float mrun = -1e30f, lrun = 0.f;
  f32x4 acc_o[8];                                   // O^T: d = 16dt+4lh+rr, q = lg
  #pragma unroll
  for (int dt = 0; dt < 8; ++dt) acc_o[dt] = (f32x4){0.f, 0.f, 0.f, 0.f};

  i32x4 kreg[2];
  int2  vreg[2][2];

#define ISSUE_LOADS(KT)                                                         \
  {                                                                             \
    int kk0 = (KT) * 64;                                                        \
    _Pragma("unroll")                                                           \
    for (int i = 0; i < 2; ++i) {                                               \
      int a = tid + i*256, r = a >> 3, c = a & 7;                               \
      kreg[i] = *(const i32x4*)&kq[((size_t)hk*TT + kk0 + r)*HD + c*16];        \
    }                                                                           \
    _Pragma("unroll")                                                           \
    for (int it = 0; it < 2; ++it) {                                            \
      int a2 = tid + it*256, m2 = a2 & 31, d0 = (a2 >> 5) * 8;                  \
      vreg[it][0] = *(const int2*)&vq[((size_t)hk*TT + kk0 + 2*m2    )*HD + d0];\
      vreg[it][1] = *(const int2*)&vq[((size_t)hk*TT + kk0 + 2*m2 + 1)*HD + d0];\
    }                                                                           \
  }

  ISSUE_LOADS(ktb);

  for (int kt = ktb; kt < kte; ++kt) {
    int k0 = kt * 64;
    __syncthreads();                                 // prev compute done with LDS
    // ---- write staged regs -> LDS ----
    #pragma unroll
    for (int i = 0; i < 2; ++i) {
      int a = tid + i*256, r = a >> 3, c = a & 7;
      *(i32x4*)&Ks[r*144 + c*16] = kreg[i];
    }
    #pragma unroll
    for (int it = 0; it < 2; ++it) {
      int a2 = tid + it*256, m2 = a2 & 31, d0 = (a2 >> 5) * 8;
      int xa = vreg[it][0].x, ya = vreg[it][0].y;
      int xb = vreg[it][1].x, yb = vreg[it][1].y;
      #pragma unroll
      for (int j = 0; j < 4; ++j) {
        int v0 = (xa << (24 - 8*j)) >> 24;
        int v1 = (xb << (24 - 8*j)) >> 24;
        uint32_t pk = (fbits((float)v0) >> 16) | ((fbits((float)v1) >> 16) << 16);
        *(uint32_t*)&Vt[(d0 + j)*72 + 2*m2] = pk;
      }
      #pragma unroll
      for (int j = 0; j < 4; ++j) {
        int v0 = (ya << (24 - 8*j)) >> 24;
        int v1 = (yb << (24 - 8*j)) >> 24;
        uint32_t pk = (fbits((float)v0) >> 16) | ((fbits((float)v1) >> 16) << 16);
        *(uint32_t*)&Vt[(d0 + 4 + j)*72 + 2*m2] = pk;
      }
    }
    __syncthreads();
    if (kt + 1 < kte) ISSUE_LOADS(kt + 1);

    // ---- swapped scores: S^T[k][q], lane owns q=lg, k = 16t+4lh+rr ----
    i32x4 sacc[4];
    #pragma unroll
    for (int t = 0; t < 4; ++t) sacc[t] = (i32x4){0, 0, 0, 0};
    #pragma unroll
    for (int t = 0; t < 4; ++t) {
      const int8_t* kp = &Ks[(16*t + lg)*144 + lh*16];
      i32x4 b0 = *(const i32x4*)kp;
      i32x4 b1 = *(const i32x4*)(kp + 64);
      sacc[t] = mfma_i8(b0, qa0, sacc[t]);     // A=K, B=Q
      sacc[t] = mfma_i8(b1, qa1, sacc[t]);
    }

    f32x4 ksv4[4], vsv4[4];
    #pragma unroll
    for (int t = 0; t < 4; ++t) {
      ksv4[t] = *(const f32x4*)&ksc_in[(size_t)hk*TT + k0 + 16*t + 4*lh];
      vsv4[t] = *(const f32x4*)&vsc_in[(size_t)hk*TT + k0 + 16*t + 4*lh];
    }

    bool maskTile = (kt == nkt_full - 1);
    float sf[4][4];
    #pragma unroll
    for (int t = 0; t < 4; ++t)
      #pragma unroll
      for (int rr = 0; rr < 4; ++rr) {
        float v = (float)sacc[t][rr] * qsl * ksv4[t][rr];
        if (maskTile) {
          int kkg = k0 + 16*t + 4*lh + rr;
          v = (kkg <= myq) ? v : -1e30f;
        }
        sf[t][rr] = v;
      }

    // ---- online softmax: lane-local 16-max/sum + 2 shfl_xor each ----
    float rm = sf[0][0];
    #pragma unroll
    for (int t = 0; t < 4; ++t)
      #pragma unroll
      for (int rr = 0; rr < 4; ++rr) rm = fmaxf(rm, sf[t][rr]);
    rm = fmaxf(rm, __shfl_xor(rm, 16));
    rm = fmaxf(rm, __shfl_xor(rm, 32));
    float mnew = fmaxf(mrun, rm);
    float corr = EXP2(mrun - mnew);
    mrun = mnew;
    float p[4][4];
    float ps = 0.f;
    #pragma unroll
    for (int t = 0; t < 4; ++t)
      #pragma unroll
      for (int rr = 0; rr < 4; ++rr) { p[t][rr] = EXP2(sf[t][rr] - mnew); ps += p[t][rr]; }
    ps += __shfl_xor(ps, 16);
    ps += __shfl_xor(ps, 32);
    lrun = lrun * corr + ps;

    // ---- P' = p*vs -> Pf[q=lg][k], 4 x b128 writes ----
    #pragma unroll
    for (int t = 0; t < 4; ++t) {
      f32x4 pw;
      #pragma unroll
      for (int rr = 0; rr < 4; ++rr) pw[rr] = p[t][rr] * vsv4[t][rr];
      *(f32x4*)&Pf[w][lg*68 + 16*t + 4*lh] = pw;
    }

    // ---- rescale O (lane-local corr) ----
    #pragma unroll
    for (int dt = 0; dt < 8; ++dt)
      #pragma unroll
      for (int rr = 0; rr < 4; ++rr) acc_o[dt][rr] *= corr;

    // ---- build split-bf16 B-frags from P' (B col = q = lg, k = kb*32+8lh..)
    s16x8 pahi[2], palo[2];
    #pragma unroll
    for (int kb = 0; kb < 2; ++kb) {
      const float* pr = &Pf[w][lg*68 + kb*32 + lh*8];
      f32x4 x0 = *(const f32x4*)pr;
      f32x4 x1 = *(const f32x4*)(pr + 4);
      float xv[8] = {x0.x, x0.y, x0.z, x0.w, x1.x, x1.y, x1.z, x1.w};
      float lv[8];
      #pragma unroll
      for (int j = 0; j < 8; ++j) {
        uint32_t hb = fbits(xv[j]) & 0xffff0000u;
        union { uint32_t u; float f; } hf; hf.u = hb;
        lv[j] = xv[j] - hf.f;
      }
      union { uint32_t u[4]; s16x8 v; } H, L;
      #pragma unroll
      for (int jj = 0; jj < 4; ++jj) {
        H.u[jj] = (fbits(xv[2*jj]) >> 16) | (fbits(xv[2*jj+1]) & 0xffff0000u);
        L.u[jj] = (fbits(lv[2*jj]) >> 16) | (fbits(lv[2*jj+1]) & 0xffff0000u);
      }
      pahi[kb] = H.v; palo[kb] = L.v;
    }

    // ---- swapped PV: A = V^T tile (row d = 16dt+lg), B = P'^T ----
    #pragma unroll
    for (int dt = 0; dt < 8; ++dt) {
      #pragma unroll
      for (int kb = 0; kb < 2; ++kb) {
        s16x8 vb = *(const s16x8*)&Vt[(16*dt + lg)*72 + kb*32 + lh*8];
        acc_o[dt] = mfma_bf16(vb, pahi[kb], acc_o[dt]);
        acc_o[dt] = mfma_bf16(vb, palo[kb], acc_o[dt]);
      }
    }
  }
#undef ISSUE_LOADS

  // ---- epilogue (all lane-local): q = myq, d = 16dt + 4lh + rr ----
  if (sp < 0) {
    float invv = 1.0f / lrun;
    size_t base = (size_t)myq*DD + (size_t)h*HD;
    #pragma unroll
    for (int dt = 0; dt < 8; ++dt) {
      ushort4 Hv, Lv;
      float v0 = acc_o[dt][0]*invv, v1 = acc_o[dt][1]*invv;
      float v2 = acc_o[dt][2]*invv, v3 = acc_o[dt][3]*invv;
      Hv.x = bf16_rne(v0); Hv.y = bf16_rne(v1); Hv.z = bf16_rne(v2); Hv.w = bf16_rne(v3);
      Lv.x = bf16_rne(v0 - bf16_to_f(Hv.x)); Lv.y = bf16_rne(v1 - bf16_to_f(Hv.y));
      Lv.z = bf16_rne(v2 - bf16_to_f(Hv.z)); Lv.w = bf16_rne(v3 - bf16_to_f(Hv.w));
      *(ushort4*)&aoh[base + 16*dt + 4*lh] = Hv;
      *(ushort4*)&aol[base + 16*dt + 4*lh] = Lv;
    }
  } else {
    int tile = h*16 + (qb - 16);
    float* op = (sp == 0 ? opart0 : opart1) + (size_t)tile*8192 + (size_t)(16*w + lg)*128;
    #pragma unroll
    for (int dt = 0; dt < 8; ++dt)
      *(f32x4*)&op[16*dt + 4*lh] = acc_o[dt];
    if (lh == 0) {
      mlm[sp*16384 + tile*64 + 16*w + lg] = mrun;
      mll[sp*16384 + tile*64 + 16*w + lg] = lrun;
    }
  }
}

// ---------------------------------------------------------------------------
// Kernel 3b: merge the two K-split halves for qb >= 16.
// Grid 256 (= 16h x 16qb), 256 threads; writes aoh/aol rows 1024..2047.
// ---------------------------------------------------------------------------
__global__ __launch_bounds__(256)
void merge_kernel(const float* __restrict__ opart0, const float* __restrict__ opart1,
                  const float* __restrict__ mlm, const float* __restrict__ mll,
                  ushort* __restrict__ aoh, ushort* __restrict__ aol) {
  int tile = blockIdx.x;
  int h = tile >> 4, j = tile & 15;
  int tid = threadIdx.x;
  int row = tid >> 2;
  int cseg = (tid & 3) * 32;
  float m1 = mlm[tile*64 + row], m2 = mlm[16384 + tile*64 + row];
  float l1 = mll[tile*64 + row], l2 = mll[16384 + tile*64 + row];
  float m = fmaxf(m1, m2);
  float c1 = EXP2(m1 - m), c2 = EXP2(m2 - m);
  float inv = 1.0f / (l1*c1 + l2*c2);
  const float* p0 = opart0 + (size_t)tile*8192 + row*128 + cseg;
  const float* p1 = opart1 + (size_t)tile*8192 + row*128 + cseg;
  size_t ob = (size_t)(1024 + j*64 + row)*DD + (size_t)h*HD + cseg;
  #pragma unroll
  for (int c4 = 0; c4 < 8; ++c4) {
    f32x4 a = *(const f32x4*)&p0[c4*4];
    f32x4 b = *(const f32x4*)&p1[c4*4];
    ushort4 Hv, Lv;
    #pragma unroll
    for (int e = 0; e < 4; ++e) {
      float v = (a[e]*c1 + b[e]*c2) * inv;
      ushort hb = bf16_rne(v);
      ushort lb = bf16_rne(v - bf16_to_f(hb));
      ((ushort*)&Hv)[e] = hb;
      ((ushort*)&Lv)[e] = lb;
    }
    *(ushort4*)&aoh[ob + c4*4] = Hv;
    *(ushort4*)&aol[ob + c4*4] = Lv;
  }
}

// ---------------------------------------------------------------------------
// Kernel 3c: split wo (f32) into hi/lo bf16.
// ---------------------------------------------------------------------------
__global__ __launch_bounds__(256)
void wcvt_kernel(const float* __restrict__ wom, ushort* __restrict__ woh,
                 ushort* __restrict__ wol) {
  size_t base = ((size_t)blockIdx.x * 256 + threadIdx.x) * 8;
  float4 a = *(const float4*)&wom[base];
  float4 b = *(const float4*)&wom[base + 4];
  float vv[8] = {a.x, a.y, a.z, a.w, b.x, b.y, b.z, b.w};
  s16x8 H, L;
  #pragma unroll
  for (int j = 0; j < 8; ++j) {
    ushort hb = bf16_rne(vv[j]);
    float lo = vv[j] - bf16_to_f(hb);
    H[j] = (short)hb;
    L[j] = (short)bf16_rne(lo);
  }
  *(s16x8*)&woh[base] = H;
  *(s16x8*)&wol[base] = L;
}

// ---------------------------------------------------------------------------
// Kernel 4: wo GEMM on bf16 MFMA with 3-product split (unchanged, verified).
// ---------------------------------------------------------------------------
__global__ __launch_bounds__(256)
void wo_gemm_kernel(const ushort* __restrict__ aoh, const ushort* __restrict__ aol,
                    const ushort* __restrict__ woh, const ushort* __restrict__ wol,
                    float* __restrict__ outp) {
  int o0 = blockIdx.x * 128;
  int t0 = blockIdx.y * 128;
  __shared__ ushort AH[128 * 72];
  __shared__ ushort AL[128 * 72];
  __shared__ ushort BH[128 * 72];
  __shared__ ushort BL[128 * 72];
  int tid = threadIdx.x;
  int wv4 = tid >> 6;
  int wr = wv4 >> 1, wc = wv4 & 1;
  int l  = tid & 63;
  int lg = l & 15;
  int lh = l >> 4;

  f32x4 acc[4][4];
  #pragma unroll
  for (int ti = 0; ti < 4; ++ti)
    #pragma unroll
    for (int tj = 0; tj < 4; ++tj) acc[ti][tj] = (f32x4){0.f,0.f,0.f,0.f};

  for (int kt = 0; kt < DD/64; ++kt) {
    int k0 = kt * 64;
    __syncthreads();
    #pragma unroll
    for (int i = 0; i < 4; ++i) {
      int idx = tid + i*256, r = idx >> 3, c = idx & 7;
      size_t ga = (size_t)(t0 + r)*DD + k0 + c*8;
      size_t gb = (size_t)(o0 + r)*DD + k0 + c*8;
      *(s16x8*)&AH[r*72 + c*8] = *(const s16x8*)&aoh[ga];
      *(s16x8*)&AL[r*72 + c*8] = *(const s16x8*)&aol[ga];
      *(s16x8*)&BH[r*72 + c*8] = *(const s16x8*)&woh[gb];
      *(s16x8*)&BL[r*72 + c*8] = *(const s16x8*)&wol[gb];
    }
    __syncthreads();
    #pragma unroll
    for (int s = 0; s < 2; ++s) {
      s16x8 ah[4], al[4];
      #pragma unroll
      for (int ti = 0; ti < 4; ++ti) {
        int ab = (wr*64 + ti*16 + lg)*72 + s*32 + lh*8;
        ah[ti] = *(const s16x8*)&AH[ab];
        al[ti] = *(const s16x8*)&AL[ab];
      }
      #pragma unroll
      for (int tj = 0; tj < 4; ++tj) {
        int bb = (wc*64 + tj*16 + lg)*72 + s*32 + lh*8;
        s16x8 bh = *(const s16x8*)&BH[bb];
        s16x8 bl = *(const s16x8*)&BL[bb];
        #pragma unroll
        for (int ti = 0; ti < 4; ++ti) {
          acc[ti][tj] = mfma_bf16(ah[ti], bh, acc[ti][tj]);
          acc[ti][tj] = mfma_bf16(ah[ti], bl, acc[ti][tj]);
          acc[ti][tj] = mfma_bf16(al[ti], bh, acc[ti][tj]);
        }
      }
    }
  }

  #pragma unroll
  for (int ti = 0; ti < 4; ++ti)
    #pragma unroll
    for (int tj = 0; tj < 4; ++tj)
      #pragma unroll
      for (int rr = 0; rr < 4; ++rr) {
        int t = t0 + wr*64 + ti*16 + lh*4 + rr;
        int o = o0 + wc*64 + tj*16 + lg;
        outp[(size_t)t*DD + o] = acc[ti][tj][rr];
      }
}

// ---------------------------------------------------------------------------
extern "C" void kernel_launch(void* const* d_in, const int* in_sizes, int n_in,
                              void* d_out, int out_size, void* d_ws, size_t ws_size,
                              hipStream_t stream) {
  (void)in_sizes; (void)n_in; (void)out_size; (void)ws_size;
  const float* x  = (const float*)d_in[0];
  const float* wq = (const float*)d_in[1];
  const float* wk = (const float*)d_in[2];
  const float* wv = (const float*)d_in[3];
  const float* wo = (const float*)d_in[4];
  float* out = (float*)d_out;

  char* ws = (char*)d_ws;
  const size_t MB = 1048576;
  int8_t* qx  = (int8_t*)(ws);           // [2048][2048]; dead after proj
  int8_t* qwq = (int8_t*)(ws + 4*MB);    // dead after proj
  int8_t* qwk = (int8_t*)(ws + 8*MB);    // dead after proj
  int8_t* qwv = (int8_t*)(ws + 9*MB);    // dead after proj
  int8_t* qqp = (int8_t*)(ws + 10*MB);   // [16][2048][128]; dead after attn
  int8_t* kqp = (int8_t*)(ws + 14*MB);   // [4][2048][128];  dead after attn
  int8_t* vqp = (int8_t*)(ws + 15*MB);   // [4][2048][128];  dead after attn
  float* xs  = (float*)(ws + 16*MB);
  float* wqs = xs + 2048;
  float* wks = wqs + 2048;
  float* wvs = wks + 512;
  float* qsc = wvs + 512;
  float* ksc = qsc + (size_t)NH*TT;
  float* vsc = ksc + (size_t)NKV*TT;
  ushort* aoh = (ushort*)(ws + 16*MB + 262144);   // 8 MB
  ushort* aol = (ushort*)(ws + 24*MB + 262144);   // 8 MB (ends 32.25 MB)
  // attn-phase scratch over dead regions:
  float* opart0 = (float*)(ws);                   // 8 MiB (over qx/qwq, dead)
  float* mlm    = (float*)(ws + 8*MB);            // 128 KB (over qwk, dead)
  float* mll    = (float*)(ws + 8*MB + 131072);   // 128 KB
  float* opart1 = out;                            // 8 MiB scratch in d_out
  // wo-phase scratch (after merge, everything below 16 MB is dead):
  ushort* woh = (ushort*)(ws);                    // 8 MB
  ushort* wol = (ushort*)(ws + 8*MB);             // 8 MB

  quant_rows_kernel<<<5120, 256, 0, stream>>>(x, wq, wk, wv,
                                              qx, xs, qwq, wqs, qwk, wks, qwv, wvs);
  proj_kernel<<<dim3(TT/128, NH + 2*NKV), 256, 0, stream>>>(
      qx, xs, qwq, wqs, qwk, wks, qwv, wvs,
      qqp, qsc, kqp, ksc, vqp, vsc);
  attn_mfma_kernel<<<768, 256, 0, stream>>>(
      qqp, qsc, kqp, ksc, vqp, vsc, aoh, aol, opart0, opart1, mlm, mll);
  merge_kernel<<<256, 256, 0, stream>>>(opart0, opart1, mlm, mll, aoh, aol);
  wcvt_kernel<<<2048, 256, 0, stream>>>(wo, woh, wol);
  wo_gemm_kernel<<<dim3(DD/128, TT/128), 256, 0, stream>>>(aoh, aol, woh, wol, out);
}

// Round 6
// 215.967 us; speedup vs baseline: 4.2563x; 1.0348x over previous
//
#include <hip/hip_runtime.h>
#include <cstdint>
#include <math.h>

#define TT 2048
#define DD 2048
#define NH 16
#define NKV 4
#define HD 128
#define SCALE_F 0.08838834764831845f
#define LOG2E 1.4426950408889634f

#if __has_builtin(__builtin_amdgcn_exp2f)
#define EXP2(x) __builtin_amdgcn_exp2f(x)
#else
#define EXP2(x) exp2f(x)
#endif

typedef int   i32x4 __attribute__((ext_vector_type(4)));
typedef float f32x4 __attribute__((ext_vector_type(4)));
typedef short s16x8 __attribute__((ext_vector_type(8)));

__device__ __forceinline__ i32x4 mfma_i8(i32x4 a, i32x4 b, i32x4 c) {
  return __builtin_amdgcn_mfma_i32_16x16x64_i8(a, b, c, 0, 0, 0);
}
__device__ __forceinline__ f32x4 mfma_bf16(s16x8 a, s16x8 b, f32x4 c) {
  return __builtin_amdgcn_mfma_f32_16x16x32_bf16(a, b, c, 0, 0, 0);
}
__device__ __forceinline__ uint32_t fbits(float f) {
  union { float f; uint32_t u; } x; x.f = f; return x.u;
}
__device__ __forceinline__ ushort bf16_rne(float v) {
  uint32_t u = fbits(v);
  return (ushort)((u + 0x7fffu + ((u >> 16) & 1u)) >> 16);
}
__device__ __forceinline__ float bf16_to_f(ushort h) {
  union { uint32_t u; float f; } x; x.u = ((uint32_t)h) << 16; return x.f;
}

// ---------------------------------------------------------------------------
// Kernel 1: rowwise symmetric int8 quantization for x, wq, wk, wv.
// ---------------------------------------------------------------------------
__global__ __launch_bounds__(256)
void quant_rows_kernel(const float* __restrict__ x, const float* __restrict__ wq,
                       const float* __restrict__ wk, const float* __restrict__ wv,
                       int8_t* __restrict__ qx, float* __restrict__ xs,
                       int8_t* __restrict__ qwq, float* __restrict__ wqs,
                       int8_t* __restrict__ qwk, float* __restrict__ wks,
                       int8_t* __restrict__ qwv, float* __restrict__ wvs) {
  int r = blockIdx.x;
  const float* src; int8_t* dst; float* sc; int row;
  if (r < 2048)      { src = x;  dst = qx;  sc = xs;  row = r; }
  else if (r < 4096) { src = wq; dst = qwq; sc = wqs; row = r - 2048; }
  else if (r < 4608) { src = wk; dst = qwk; sc = wks; row = r - 4096; }
  else               { src = wv; dst = qwv; sc = wvs; row = r - 4608; }
  src += (size_t)row * DD; dst += (size_t)row * DD;
  int tid = threadIdx.x;
  float4 v0 = ((const float4*)src)[2*tid];
  float4 v1 = ((const float4*)src)[2*tid+1];
  float m = fmaxf(fmaxf(fmaxf(fabsf(v0.x), fabsf(v0.y)), fmaxf(fabsf(v0.z), fabsf(v0.w))),
                  fmaxf(fmaxf(fabsf(v1.x), fabsf(v1.y)), fmaxf(fabsf(v1.z), fabsf(v1.w))));
  #pragma unroll
  for (int off = 1; off < 64; off <<= 1) m = fmaxf(m, __shfl_xor(m, off));
  __shared__ float wmax[4];
  if ((tid & 63) == 0) wmax[tid >> 6] = m;
  __syncthreads();
  m = fmaxf(fmaxf(wmax[0], wmax[1]), fmaxf(wmax[2], wmax[3]));
  float s = fmaxf(m / 127.0f, 1e-8f);
  if (tid == 0) sc[row] = s;
  float vv[8] = {v0.x, v0.y, v0.z, v0.w, v1.x, v1.y, v1.z, v1.w};
  uint32_t p0 = 0, p1 = 0;
  #pragma unroll
  for (int i = 0; i < 4; ++i) {
    int q = (int)fminf(fmaxf(rintf(vv[i] / s), -127.0f), 127.0f);
    p0 |= ((uint32_t)q & 0xffu) << (8*i);
  }
  #pragma unroll
  for (int i = 0; i < 4; ++i) {
    int q = (int)fminf(fmaxf(rintf(vv[4+i] / s), -127.0f), 127.0f);
    p1 |= ((uint32_t)q & 0xffu) << (8*i);
  }
  ((uint2*)dst)[tid] = make_uint2(p0, p1);
}

// ---------------------------------------------------------------------------
// Kernel 2: i8-MFMA projection GEMM + dequant + RoPE + rowwise requant.
// Round 6: tile 64t x 128o, 128 threads (2 waves x 32t), grid 768 blocks
// (~4 co-resident blocks/CU for TLP), register prefetch of next K-tile
// (12 x dwordx4 per thread) to hide global latency under MFMA.
// Per-wave math identical to the round-4-verified version.
// ---------------------------------------------------------------------------
__global__ __launch_bounds__(128)
void proj_kernel(const int8_t* __restrict__ qx, const float* __restrict__ xs,
                 const int8_t* __restrict__ qwq, const float* __restrict__ wqs,
                 const int8_t* __restrict__ qwk, const float* __restrict__ wks,
                 const int8_t* __restrict__ qwv, const float* __restrict__ wvs,
                 int8_t* __restrict__ qq, float* __restrict__ qsc_out,
                 int8_t* __restrict__ kq, float* __restrict__ ksc_out,
                 int8_t* __restrict__ vq, float* __restrict__ vsc_out) {
  int gh = blockIdx.y;
  int t0 = blockIdx.x * 64;
  const int8_t* wgt; const float* wsc; int8_t* outq; float* outs; bool doRope;
  if (gh < NH) {
    wgt = qwq + (size_t)gh*HD*DD; wsc = wqs + gh*HD;
    outq = qq + (size_t)gh*TT*HD; outs = qsc_out + (size_t)gh*TT; doRope = true;
  } else if (gh < NH + NKV) {
    int hh = gh - NH;
    wgt = qwk + (size_t)hh*HD*DD; wsc = wks + hh*HD;
    outq = kq + (size_t)hh*TT*HD; outs = ksc_out + (size_t)hh*TT; doRope = true;
  } else {
    int hh = gh - NH - NKV;
    wgt = qwv + (size_t)hh*HD*DD; wsc = wvs + hh*HD;
    outq = vq + (size_t)hh*TT*HD; outs = vsc_out + (size_t)hh*TT; doRope = false;
  }

  __shared__ int8_t As[64 * 144];    // [t][k], 144B row stride
  __shared__ int8_t Bs[128 * 144];   // [o][k]
  int tid = threadIdx.x;
  int w  = tid >> 6;    // wave: t rows w*32 .. +31
  int l  = tid & 63;
  int lg = l & 15;
  int lh = l >> 4;

  i32x4 acc[2][8];
  #pragma unroll
  for (int ti = 0; ti < 2; ++ti)
    #pragma unroll
    for (int tj = 0; tj < 8; ++tj) acc[ti][tj] = (i32x4){0,0,0,0};

  i32x4 prefA[4], prefB[8];

#define PROJ_ISSUE(KT)                                                          \
  {                                                                             \
    int kk0 = (KT) * 128;                                                       \
    _Pragma("unroll")                                                           \
    for (int i = 0; i < 4; ++i) {                                               \
      int idx = tid + i*128, r = idx >> 3, c = idx & 7;                         \
      prefA[i] = *(const i32x4*)&qx[(size_t)(t0 + r)*DD + kk0 + c*16];          \
    }                                                                           \
    _Pragma("unroll")                                                           \
    for (int i = 0; i < 8; ++i) {                                               \
      int idx = tid + i*128, r = idx >> 3, c = idx & 7;                         \
      prefB[i] = *(const i32x4*)&wgt[(size_t)r*DD + kk0 + c*16];                \
    }                                                                           \
  }

  PROJ_ISSUE(0);

  for (int kt = 0; kt < DD/128; ++kt) {
    __syncthreads();   // prev compute done with As/Bs
    #pragma unroll
    for (int i = 0; i < 4; ++i) {
      int idx = tid + i*128, r = idx >> 3, c = idx & 7;
      *(i32x4*)&As[r*144 + c*16] = prefA[i];
    }
    #pragma unroll
    for (int i = 0; i < 8; ++i) {
      int idx = tid + i*128, r = idx >> 3, c = idx & 7;
      *(i32x4*)&Bs[r*144 + c*16] = prefB[i];
    }
    __syncthreads();
    if (kt + 1 < DD/128) PROJ_ISSUE(kt + 1);

    #pragma unroll
    for (int s = 0; s < 2; ++s) {
      i32x4 a0 = *(const i32x4*)&As[(w*32 + lg)*144      + s*64 + lh*16];
      i32x4 a1 = *(const i32x4*)&As[(w*32 + 16 + lg)*144 + s*64 + lh*16];
      #pragma unroll
      for (int tj = 0; tj < 8; ++tj) {
        i32x4 b = *(const i32x4*)&Bs[(tj*16 + lg)*144 + s*64 + lh*16];
        acc[0][tj] = mfma_i8(a0, b, acc[0][tj]);
        acc[1][tj] = mfma_i8(a1, b, acc[1][tj]);
      }
    }
  }
#undef PROJ_ISSUE

  // ---- epilogue: dequant -> RoPE -> rowwise requant (verified structure) ----
  float y[2][8][4];
  #pragma unroll
  for (int ti = 0; ti < 2; ++ti)
    #pragma unroll
    for (int rr = 0; rr < 4; ++rr) {
      int tl = w*32 + ti*16 + lh*4 + rr;
      float xsi = xs[t0 + tl];
      #pragma unroll
      for (int tj = 0; tj < 8; ++tj)
        y[ti][tj][rr] = (float)acc[ti][tj][rr] * xsi * wsc[tj*16 + lg];
    }

  if (doRope) {
    float invf[4];
    #pragma unroll
    for (int tj = 0; tj < 4; ++tj)
      invf[tj] = 1.0f / powf(1000000.0f, (float)(tj*16 + lg) * (1.0f/64.0f));
    #pragma unroll
    for (int ti = 0; ti < 2; ++ti)
      #pragma unroll
      for (int rr = 0; rr < 4; ++rr) {
        float trow = (float)(t0 + w*32 + ti*16 + lh*4 + rr);
        #pragma unroll
        for (int tj = 0; tj < 4; ++tj) {
          float sn, cs;
          sincosf(trow * invf[tj], &sn, &cs);
          float lo = y[ti][tj][rr], hi = y[ti][tj+4][rr];
          y[ti][tj][rr]   = lo*cs - hi*sn;
          y[ti][tj+4][rr] = hi*cs + lo*sn;
        }
      }
  }

  __syncthreads();   // all waves done reading As/Bs; reuse As for output tile
  #pragma unroll
  for (int ti = 0; ti < 2; ++ti)
    #pragma unroll
    for (int rr = 0; rr < 4; ++rr) {
      int tl = w*32 + ti*16 + lh*4 + rr;
      float mx = fabsf(y[ti][0][rr]);
      #pragma unroll
      for (int tj = 1; tj < 8; ++tj) mx = fmaxf(mx, fabsf(y[ti][tj][rr]));
      mx = fmaxf(mx, __shfl_xor(mx, 1));
      mx = fmaxf(mx, __shfl_xor(mx, 2));
      mx = fmaxf(mx, __shfl_xor(mx, 4));
      mx = fmaxf(mx, __shfl_xor(mx, 8));
      float s = fmaxf(mx / 127.0f, 1e-8f);
      if (lg == 0) outs[t0 + tl] = s;
      #pragma unroll
      for (int tj = 0; tj < 8; ++tj) {
        int qv = (int)fminf(fmaxf(rintf(y[ti][tj][rr] / s), -127.0f), 127.0f);
        As[tl*144 + tj*16 + lg] = (int8_t)qv;
      }
    }
  __syncthreads();
  #pragma unroll
  for (int i = 0; i < 4; ++i) {
    int idx = tid + i*128, r = idx >> 3, c = idx & 7;
    *(i32x4*)&outq[(size_t)(t0 + r)*HD + c*16] = *(const i32x4*)&As[r*144 + c*16];
  }
}

// ---------------------------------------------------------------------------
// Kernel 3: MFMA flash attention, operand-swapped, K-split, reg-prefetch.
// (unchanged from round 5 — verified)
// ---------------------------------------------------------------------------
__global__ __launch_bounds__(256)
void attn_mfma_kernel(const int8_t* __restrict__ qq, const float* __restrict__ qsc_in,
                      const int8_t* __restrict__ kq, const float* __restrict__ ksc_in,
                      const int8_t* __restrict__ vq, const float* __restrict__ vsc_in,
                      ushort* __restrict__ aoh, ushort* __restrict__ aol,
                      float* __restrict__ opart0, float* __restrict__ opart1,
                      float* __restrict__ mlm, float* __restrict__ mll) {
  int id = blockIdx.x;
  int h, qb, sp, ktb, kte;
  if (id < 512) {
    sp = id & 1;
    int r = id >> 1;
    h  = r & 15;
    qb = 31 - (r >> 4);
    int nkt = qb + 1, mid = nkt >> 1;
    ktb = sp ? mid : 0;
    kte = sp ? nkt : mid;
  } else {
    int r = id - 512;
    h  = r & 15;
    qb = 15 - (r >> 4);
    sp = -1;
    ktb = 0; kte = qb + 1;
  }
  int hk  = h >> 2;
  int qb0 = qb * 64;
  int nkt_full = qb + 1;

  __shared__ int8_t Ks[64 * 144];
  __shared__ ushort Vt[128 * 72];
  __shared__ float  Pf[4][16 * 68];

  int tid = threadIdx.x;
  int w  = tid >> 6;
  int l  = tid & 63;
  int lg = l & 15;
  int lh = l >> 4;

  const int8_t* qp = &qq[((size_t)h*TT + qb0 + 16*w + lg)*HD + lh*16];
  i32x4 qa0 = *(const i32x4*)qp;
  i32x4 qa1 = *(const i32x4*)(qp + 64);

  int myq = qb0 + 16*w + lg;
  float qsl = qsc_in[(size_t)h*TT + myq] * (SCALE_F * LOG2E);

  float mrun = -1e30f, lrun = 0.f;
  f32x4 acc_o[8];
  #pragma unroll
  for (int dt = 0; dt < 8; ++dt) acc_o[dt] = (f32x4){0.f, 0.f, 0.f, 0.f};

  i32x4 kreg[2];
  int2  vreg[2][2];

#define ISSUE_LOADS(KT)                                                         \
  {                                                                             \
    int kk0 = (KT) * 64;                                                        \
    _Pragma("unroll")                                                           \
    for (int i = 0; i < 2; ++i) {                                               \
      int a = tid + i*256, r = a >> 3, c = a & 7;                               \
      kreg[i] = *(const i32x4*)&kq[((size_t)hk*TT + kk0 + r)*HD + c*16];        \
    }                                                                           \
    _Pragma("unroll")                                                           \
    for (int it = 0; it < 2; ++it) {                                            \
      int a2 = tid + it*256, m2 = a2 & 31, d0 = (a2 >> 5) * 8;                  \
      vreg[it][0] = *(const int2*)&vq[((size_t)hk*TT + kk0 + 2*m2    )*HD + d0];\
      vreg[it][1] = *(const int2*)&vq[((size_t)hk*TT + kk0 + 2*m2 + 1)*HD + d0];\
    }                                                                           \
  }

  ISSUE_LOADS(ktb);

  for (int kt = ktb; kt < kte; ++kt) {
    int k0 = kt * 64;
    __syncthreads();
    #pragma unroll
    for (int i = 0; i < 2; ++i) {
      int a = tid + i*256, r = a >> 3, c = a & 7;
      *(i32x4*)&Ks[r*144 + c*16] = kreg[i];
    }
    #pragma unroll
    for (int it = 0; it < 2; ++it) {
      int a2 = tid + it*256, m2 = a2 & 31, d0 = (a2 >> 5) * 8;
      int xa = vreg[it][0].x, ya = vreg[it][0].y;
      int xb = vreg[it][1].x, yb = vreg[it][1].y;
      #pragma unroll
      for (int j = 0; j < 4; ++j) {
        int v0 = (xa << (24 - 8*j)) >> 24;
        int v1 = (xb << (24 - 8*j)) >> 24;
        uint32_t pk = (fbits((float)v0) >> 16) | ((fbits((float)v1) >> 16) << 16);
        *(uint32_t*)&Vt[(d0 + j)*72 + 2*m2] = pk;
      }
      #pragma unroll
      for (int j = 0; j < 4; ++j) {
        int v0 = (ya << (24 - 8*j)) >> 24;
        int v1 = (yb << (24 - 8*j)) >> 24;
        uint32_t pk = (fbits((float)v0) >> 16) | ((fbits((float)v1) >> 16) << 16);
        *(uint32_t*)&Vt[(d0 + 4 + j)*72 + 2*m2] = pk;
      }
    }
    __syncthreads();
    if (kt + 1 < kte) ISSUE_LOADS(kt + 1);

    i32x4 sacc[4];
    #pragma unroll
    for (int t = 0; t < 4; ++t) sacc[t] = (i32x4){0, 0, 0, 0};
    #pragma unroll
    for (int t = 0; t < 4; ++t) {
      const int8_t* kp = &Ks[(16*t + lg)*144 + lh*16];
      i32x4 b0 = *(const i32x4*)kp;
      i32x4 b1 = *(const i32x4*)(kp + 64);
      sacc[t] = mfma_i8(b0, qa0, sacc[t]);
      sacc[t] = mfma_i8(b1, qa1, sacc[t]);
    }

    f32x4 ksv4[4], vsv4[4];
    #pragma unroll
    for (int t = 0; t < 4; ++t) {
      ksv4[t] = *(const f32x4*)&ksc_in[(size_t)hk*TT + k0 + 16*t + 4*lh];
      vsv4[t] = *(const f32x4*)&vsc_in[(size_t)hk*TT + k0 + 16*t + 4*lh];
    }

    bool maskTile = (kt == nkt_full - 1);
    float sf[4][4];
    #pragma unroll
    for (int t = 0; t < 4; ++t)
      #pragma unroll
      for (int rr = 0; rr < 4; ++rr) {
        float v = (float)sacc[t][rr] * qsl * ksv4[t][rr];
        if (maskTile) {
          int kkg = k0 + 16*t + 4*lh + rr;
          v = (kkg <= myq) ? v : -1e30f;
        }
        sf[t][rr] = v;
      }

    float rm = sf[0][0];
    #pragma unroll
    for (int t = 0; t < 4; ++t)
      #pragma unroll
      for (int rr = 0; rr < 4; ++rr) rm = fmaxf(rm, sf[t][rr]);
    rm = fmaxf(rm, __shfl_xor(rm, 16));
    rm = fmaxf(rm, __shfl_xor(rm, 32));
    float mnew = fmaxf(mrun, rm);
    float corr = EXP2(mrun - mnew);
    mrun = mnew;
    float p[4][4];
    float ps = 0.f;
    #pragma unroll
    for (int t = 0; t < 4; ++t)
      #pragma unroll
      for (int rr = 0; rr < 4; ++rr) { p[t][rr] = EXP2(sf[t][rr] - mnew); ps += p[t][rr]; }
    ps += __shfl_xor(ps, 16);
    ps += __shfl_xor(ps, 32);
    lrun = lrun * corr + ps;

    #pragma unroll
    for (int t = 0; t < 4; ++t) {
      f32x4 pw;
      #pragma unroll
      for (int rr = 0; rr < 4; ++rr) pw[rr] = p[t][rr] * vsv4[t][rr];
      *(f32x4*)&Pf[w][lg*68 + 16*t + 4*lh] = pw;
    }

    #pragma unroll
    for (int dt = 0; dt < 8; ++dt)
      #pragma unroll
      for (int rr = 0; rr < 4; ++rr) acc_o[dt][rr] *= corr;

    s16x8 pahi[2], palo[2];
    #pragma unroll
    for (int kb = 0; kb < 2; ++kb) {
      const float* pr = &Pf[w][lg*68 + kb*32 + lh*8];
      f32x4 x0 = *(const f32x4*)pr;
      f32x4 x1 = *(const f32x4*)(pr + 4);
      float xv[8] = {x0.x, x0.y, x0.z, x0.w, x1.x, x1.y, x1.z, x1.w};
      float lv[8];
      #pragma unroll
      for (int j = 0; j < 8; ++j) {
        uint32_t hb = fbits(xv[j]) & 0xffff0000u;
        union { uint32_t u; float f; } hf; hf.u = hb;
        lv[j] = xv[j] - hf.f;
      }
      union { uint32_t u[4]; s16x8 v; } H, L;
      #pragma unroll
      for (int jj = 0; jj < 4; ++jj) {
        H.u[jj] = (fbits(xv[2*jj]) >> 16) | (fbits(xv[2*jj+1]) & 0xffff0000u);
        L.u[jj] = (fbits(lv[2*jj]) >> 16) | (fbits(lv[2*jj+1]) & 0xffff0000u);
      }
      pahi[kb] = H.v; palo[kb] = L.v;
    }

    #pragma unroll
    for (int dt = 0; dt < 8; ++dt) {
      #pragma unroll
      for (int kb = 0; kb < 2; ++kb) {
        s16x8 vb = *(const s16x8*)&Vt[(16*dt + lg)*72 + kb*32 + lh*8];
        acc_o[dt] = mfma_bf16(vb, pahi[kb], acc_o[dt]);
        acc_o[dt] = mfma_bf16(vb, palo[kb], acc_o[dt]);
      }
    }
  }
#undef ISSUE_LOADS

  if (sp < 0) {
    float invv = 1.0f / lrun;
    size_t base = (size_t)myq*DD + (size_t)h*HD;
    #pragma unroll
    for (int dt = 0; dt < 8; ++dt) {
      ushort4 Hv, Lv;
      float v0 = acc_o[dt][0]*invv, v1 = acc_o[dt][1]*invv;
      float v2 = acc_o[dt][2]*invv, v3 = acc_o[dt][3]*invv;
      Hv.x = bf16_rne(v0); Hv.y = bf16_rne(v1); Hv.z = bf16_rne(v2); Hv.w = bf16_rne(v3);
      Lv.x = bf16_rne(v0 - bf16_to_f(Hv.x)); Lv.y = bf16_rne(v1 - bf16_to_f(Hv.y));
      Lv.z = bf16_rne(v2 - bf16_to_f(Hv.z)); Lv.w = bf16_rne(v3 - bf16_to_f(Hv.w));
      *(ushort4*)&aoh[base + 16*dt + 4*lh] = Hv;
      *(ushort4*)&aol[base + 16*dt + 4*lh] = Lv;
    }
  } else {
    int tile = h*16 + (qb - 16);
    float* op = (sp == 0 ? opart0 : opart1) + (size_t)tile*8192 + (size_t)(16*w + lg)*128;
    #pragma unroll
    for (int dt = 0; dt < 8; ++dt)
      *(f32x4*)&op[16*dt + 4*lh] = acc_o[dt];
    if (lh == 0) {
      mlm[sp*16384 + tile*64 + 16*w + lg] = mrun;
      mll[sp*16384 + tile*64 + 16*w + lg] = lrun;
    }
  }
}

// ---------------------------------------------------------------------------
// Kernel 3b: merge the two K-split halves for qb >= 16.
// ---------------------------------------------------------------------------
__global__ __launch_bounds__(256)
void merge_kernel(const float* __restrict__ opart0, const float* __restrict__ opart1,
                  const float* __restrict__ mlm, const float* __restrict__ mll,
                  ushort* __restrict__ aoh, ushort* __restrict__ aol) {
  int tile = blockIdx.x;
  int h = tile >> 4, j = tile & 15;
  int tid = threadIdx.x;
  int row = tid >> 2;
  int cseg = (tid & 3) * 32;
  float m1 = mlm[tile*64 + row], m2 = mlm[16384 + tile*64 + row];
  float l1 = mll[tile*64 + row], l2 = mll[16384 + tile*64 + row];
  float m = fmaxf(m1, m2);
  float c1 = EXP2(m1 - m), c2 = EXP2(m2 - m);
  float inv = 1.0f / (l1*c1 + l2*c2);
  const float* p0 = opart0 + (size_t)tile*8192 + row*128 + cseg;
  const float* p1 = opart1 + (size_t)tile*8192 + row*128 + cseg;
  size_t ob = (size_t)(1024 + j*64 + row)*DD + (size_t)h*HD + cseg;
  #pragma unroll
  for (int c4 = 0; c4 < 8; ++c4) {
    f32x4 a = *(const f32x4*)&p0[c4*4];
    f32x4 b = *(const f32x4*)&p1[c4*4];
    ushort4 Hv, Lv;
    #pragma unroll
    for (int e = 0; e < 4; ++e) {
      float v = (a[e]*c1 + b[e]*c2) * inv;
      ushort hb = bf16_rne(v);
      ushort lb = bf16_rne(v - bf16_to_f(hb));
      ((ushort*)&Hv)[e] = hb;
      ((ushort*)&Lv)[e] = lb;
    }
    *(ushort4*)&aoh[ob + c4*4] = Hv;
    *(ushort4*)&aol[ob + c4*4] = Lv;
  }
}

// ---------------------------------------------------------------------------
// Kernel 3c: split wo (f32) into hi/lo bf16.
// ---------------------------------------------------------------------------
__global__ __launch_bounds__(256)
void wcvt_kernel(const float* __restrict__ wom, ushort* __restrict__ woh,
                 ushort* __restrict__ wol) {
  size_t base = ((size_t)blockIdx.x * 256 + threadIdx.x) * 8;
  float4 a = *(const float4*)&wom[base];
  float4 b = *(const float4*)&wom[base + 4];
  float vv[8] = {a.x, a.y, a.z, a.w, b.x, b.y, b.z, b.w};
  s16x8 H, L;
  #pragma unroll
  for (int j = 0; j < 8; ++j) {
    ushort hb = bf16_rne(vv[j]);
    float lo = vv[j] - bf16_to_f(hb);
    H[j] = (short)hb;
    L[j] = (short)bf16_rne(lo);
  }
  *(s16x8*)&woh[base] = H;
  *(s16x8*)&wol[base] = L;
}

// ---------------------------------------------------------------------------
// Kernel 4: wo GEMM on bf16 MFMA with 3-product split (unchanged, verified).
// ---------------------------------------------------------------------------
__global__ __launch_bounds__(256)
void wo_gemm_kernel(const ushort* __restrict__ aoh, const ushort* __restrict__ aol,
                    const ushort* __restrict__ woh, const ushort* __restrict__ wol,
                    float* __restrict__ outp) {
  int o0 = blockIdx.x * 128;
  int t0 = blockIdx.y * 128;
  __shared__ ushort AH[128 * 72];
  __shared__ ushort AL[128 * 72];
  __shared__ ushort BH[128 * 72];
  __shared__ ushort BL[128 * 72];
  int tid = threadIdx.x;
  int wv4 = tid >> 6;
  int wr = wv4 >> 1, wc = wv4 & 1;
  int l  = tid & 63;
  int lg = l & 15;
  int lh = l >> 4;

  f32x4 acc[4][4];
  #pragma unroll
  for (int ti = 0; ti < 4; ++ti)
    #pragma unroll
    for (int tj = 0; tj < 4; ++tj) acc[ti][tj] = (f32x4){0.f,0.f,0.f,0.f};

  for (int kt = 0; kt < DD/64; ++kt) {
    int k0 = kt * 64;
    __syncthreads();
    #pragma unroll
    for (int i = 0; i < 4; ++i) {
      int idx = tid + i*256, r = idx >> 3, c = idx & 7;
      size_t ga = (size_t)(t0 + r)*DD + k0 + c*8;
      size_t gb = (size_t)(o0 + r)*DD + k0 + c*8;
      *(s16x8*)&AH[r*72 + c*8] = *(const s16x8*)&aoh[ga];
      *(s16x8*)&AL[r*72 + c*8] = *(const s16x8*)&aol[ga];
      *(s16x8*)&BH[r*72 + c*8] = *(const s16x8*)&woh[gb];
      *(s16x8*)&BL[r*72 + c*8] = *(const s16x8*)&wol[gb];
    }
    __syncthreads();
    #pragma unroll
    for (int s = 0; s < 2; ++s) {
      s16x8 ah[4], al[4];
      #pragma unroll
      for (int ti = 0; ti < 4; ++ti) {
        int ab = (wr*64 + ti*16 + lg)*72 + s*32 + lh*8;
        ah[ti] = *(const s16x8*)&AH[ab];
        al[ti] = *(const s16x8*)&AL[ab];
      }
      #pragma unroll
      for (int tj = 0; tj < 4; ++tj) {
        int bb = (wc*64 + tj*16 + lg)*72 + s*32 + lh*8;
        s16x8 bh = *(const s16x8*)&BH[bb];
        s16x8 bl = *(const s16x8*)&BL[bb];
        #pragma unroll
        for (int ti = 0; ti < 4; ++ti) {
          acc[ti][tj] = mfma_bf16(ah[ti], bh, acc[ti][tj]);
          acc[ti][tj] = mfma_bf16(ah[ti], bl, acc[ti][tj]);
          acc[ti][tj] = mfma_bf16(al[ti], bh, acc[ti][tj]);
        }
      }
    }
  }

  #pragma unroll
  for (int ti = 0; ti < 4; ++ti)
    #pragma unroll
    for (int tj = 0; tj < 4; ++tj)
      #pragma unroll
      for (int rr = 0; rr < 4; ++rr) {
        int t = t0 + wr*64 + ti*16 + lh*4 + rr;
        int o = o0 + wc*64 + tj*16 + lg;
        outp[(size_t)t*DD + o] = acc[ti][tj][rr];
      }
}

// ---------------------------------------------------------------------------
extern "C" void kernel_launch(void* const* d_in, const int* in_sizes, int n_in,
                              void* d_out, int out_size, void* d_ws, size_t ws_size,
                              hipStream_t stream) {
  (void)in_sizes; (void)n_in; (void)out_size; (void)ws_size;
  const float* x  = (const float*)d_in[0];
  const float* wq = (const float*)d_in[1];
  const float* wk = (const float*)d_in[2];
  const float* wv = (const float*)d_in[3];
  const float* wo = (const float*)d_in[4];
  float* out = (float*)d_out;

  char* ws = (char*)d_ws;
  const size_t MB = 1048576;
  int8_t* qx  = (int8_t*)(ws);           // [2048][2048]; dead after proj
  int8_t* qwq = (int8_t*)(ws + 4*MB);    // dead after proj
  int8_t* qwk = (int8_t*)(ws + 8*MB);    // dead after proj
  int8_t* qwv = (int8_t*)(ws + 9*MB);    // dead after proj
  int8_t* qqp = (int8_t*)(ws + 10*MB);   // [16][2048][128]; dead after attn
  int8_t* kqp = (int8_t*)(ws + 14*MB);   // [4][2048][128];  dead after attn
  int8_t* vqp = (int8_t*)(ws + 15*MB);   // [4][2048][128];  dead after attn
  float* xs  = (float*)(ws + 16*MB);
  float* wqs = xs + 2048;
  float* wks = wqs + 2048;
  float* wvs = wks + 512;
  float* qsc = wvs + 512;
  float* ksc = qsc + (size_t)NH*TT;
  float* vsc = ksc + (size_t)NKV*TT;
  ushort* aoh = (ushort*)(ws + 16*MB + 262144);   // 8 MB
  ushort* aol = (ushort*)(ws + 24*MB + 262144);   // 8 MB (ends 32.25 MB)
  // attn-phase scratch over dead regions:
  float* opart0 = (float*)(ws);                   // 8 MiB (over qx/qwq, dead)
  float* mlm    = (float*)(ws + 8*MB);            // 128 KB (over qwk, dead)
  float* mll    = (float*)(ws + 8*MB + 131072);   // 128 KB
  float* opart1 = out;                            // 8 MiB scratch in d_out
  // wo-phase scratch (after merge, everything below 16 MB is dead):
  ushort* woh = (ushort*)(ws);                    // 8 MB
  ushort* wol = (ushort*)(ws + 8*MB);             // 8 MB

  quant_rows_kernel<<<5120, 256, 0, stream>>>(x, wq, wk, wv,
                                              qx, xs, qwq, wqs, qwk, wks, qwv, wvs);
  proj_kernel<<<dim3(TT/64, NH + 2*NKV), 128, 0, stream>>>(
      qx, xs, qwq, wqs, qwk, wks, qwv, wvs,
      qqp, qsc, kqp, ksc, vqp, vsc);
  attn_mfma_kernel<<<768, 256, 0, stream>>>(
      qqp, qsc, kqp, ksc, vqp, vsc, aoh, aol, opart0, opart1, mlm, mll);
  merge_kernel<<<256, 256, 0, stream>>>(opart0, opart1, mlm, mll, aoh, aol);
  wcvt_kernel<<<2048, 256, 0, stream>>>(wo, woh, wol);
  wo_gemm_kernel<<<dim3(DD/128, TT/128), 256, 0, stream>>>(aoh, aol, woh, wol, out);
}

// Round 7
// 215.937 us; speedup vs baseline: 4.2569x; 1.0001x over previous
//
#include <hip/hip_runtime.h>
#include <cstdint>
#include <math.h>

#define TT 2048
#define DD 2048
#define NH 16
#define NKV 4
#define HD 128
#define SCALE_F 0.08838834764831845f
#define LOG2E 1.4426950408889634f

#if __has_builtin(__builtin_amdgcn_exp2f)
#define EXP2(x) __builtin_amdgcn_exp2f(x)
#else
#define EXP2(x) exp2f(x)
#endif

typedef int   i32x4 __attribute__((ext_vector_type(4)));
typedef float f32x4 __attribute__((ext_vector_type(4)));
typedef short s16x8 __attribute__((ext_vector_type(8)));

__device__ __forceinline__ i32x4 mfma_i8(i32x4 a, i32x4 b, i32x4 c) {
  return __builtin_amdgcn_mfma_i32_16x16x64_i8(a, b, c, 0, 0, 0);
}
__device__ __forceinline__ f32x4 mfma_bf16(s16x8 a, s16x8 b, f32x4 c) {
  return __builtin_amdgcn_mfma_f32_16x16x32_bf16(a, b, c, 0, 0, 0);
}
__device__ __forceinline__ uint32_t fbits(float f) {
  union { float f; uint32_t u; } x; x.f = f; return x.u;
}
__device__ __forceinline__ ushort bf16_rne(float v) {
  uint32_t u = fbits(v);
  return (ushort)((u + 0x7fffu + ((u >> 16) & 1u)) >> 16);
}
__device__ __forceinline__ float bf16_to_f(ushort h) {
  union { uint32_t u; float f; } x; x.u = ((uint32_t)h) << 16; return x.f;
}

// ---------------------------------------------------------------------------
// Kernel 1: rowwise symmetric int8 quantization for x, wq, wk, wv.
// ---------------------------------------------------------------------------
__global__ __launch_bounds__(256)
void quant_rows_kernel(const float* __restrict__ x, const float* __restrict__ wq,
                       const float* __restrict__ wk, const float* __restrict__ wv,
                       int8_t* __restrict__ qx, float* __restrict__ xs,
                       int8_t* __restrict__ qwq, float* __restrict__ wqs,
                       int8_t* __restrict__ qwk, float* __restrict__ wks,
                       int8_t* __restrict__ qwv, float* __restrict__ wvs) {
  int r = blockIdx.x;
  const float* src; int8_t* dst; float* sc; int row;
  if (r < 2048)      { src = x;  dst = qx;  sc = xs;  row = r; }
  else if (r < 4096) { src = wq; dst = qwq; sc = wqs; row = r - 2048; }
  else if (r < 4608) { src = wk; dst = qwk; sc = wks; row = r - 4096; }
  else               { src = wv; dst = qwv; sc = wvs; row = r - 4608; }
  src += (size_t)row * DD; dst += (size_t)row * DD;
  int tid = threadIdx.x;
  float4 v0 = ((const float4*)src)[2*tid];
  float4 v1 = ((const float4*)src)[2*tid+1];
  float m = fmaxf(fmaxf(fmaxf(fabsf(v0.x), fabsf(v0.y)), fmaxf(fabsf(v0.z), fabsf(v0.w))),
                  fmaxf(fmaxf(fabsf(v1.x), fabsf(v1.y)), fmaxf(fabsf(v1.z), fabsf(v1.w))));
  #pragma unroll
  for (int off = 1; off < 64; off <<= 1) m = fmaxf(m, __shfl_xor(m, off));
  __shared__ float wmax[4];
  if ((tid & 63) == 0) wmax[tid >> 6] = m;
  __syncthreads();
  m = fmaxf(fmaxf(wmax[0], wmax[1]), fmaxf(wmax[2], wmax[3]));
  float s = fmaxf(m / 127.0f, 1e-8f);
  if (tid == 0) sc[row] = s;
  float vv[8] = {v0.x, v0.y, v0.z, v0.w, v1.x, v1.y, v1.z, v1.w};
  uint32_t p0 = 0, p1 = 0;
  #pragma unroll
  for (int i = 0; i < 4; ++i) {
    int q = (int)fminf(fmaxf(rintf(vv[i] / s), -127.0f), 127.0f);
    p0 |= ((uint32_t)q & 0xffu) << (8*i);
  }
  #pragma unroll
  for (int i = 0; i < 4; ++i) {
    int q = (int)fminf(fmaxf(rintf(vv[4+i] / s), -127.0f), 127.0f);
    p1 |= ((uint32_t)q & 0xffu) << (8*i);
  }
  ((uint2*)dst)[tid] = make_uint2(p0, p1);
}

// ---------------------------------------------------------------------------
// Kernel 2: i8-MFMA projection GEMM + dequant + RoPE + rowwise requant.
// Round 7: XCD-aware bijective block partition. Grid 768 linear; block id ->
// XCD id&7 (HW round-robin). Each XCD owns 6 heads x half-t: weight slabs
// 1.5 MB + qx half 2 MB = 3.5 MB -> fits the 4 MB per-XCD L2, so K-step
// staging becomes L2-resident after first touch (was: 8-way cross-XCD
// duplication, every step an HBM miss). Math identical to round 6.
// ---------------------------------------------------------------------------
__global__ __launch_bounds__(128)
void proj_kernel(const int8_t* __restrict__ qx, const float* __restrict__ xs,
                 const int8_t* __restrict__ qwq, const float* __restrict__ wqs,
                 const int8_t* __restrict__ qwk, const float* __restrict__ wks,
                 const int8_t* __restrict__ qwv, const float* __restrict__ wvs,
                 int8_t* __restrict__ qq, float* __restrict__ qsc_out,
                 int8_t* __restrict__ kq, float* __restrict__ ksc_out,
                 int8_t* __restrict__ vq, float* __restrict__ vsc_out) {
  // --- XCD-aware bijective decode: id -> (gh, tb) ---
  int id  = blockIdx.x;          // 0..767
  int xcd = id & 7;
  int j   = id >> 3;             // 0..95
  int hg  = xcd >> 1;            // head group 0..3 (6 heads each)
  int th  = xcd & 1;             // t half
  int gh  = hg*6 + (j % 6);      // 0..23
  int tb  = th*16 + (j / 6);     // 0..31
  int t0  = tb * 64;

  const int8_t* wgt; const float* wsc; int8_t* outq; float* outs; bool doRope;
  if (gh < NH) {
    wgt = qwq + (size_t)gh*HD*DD; wsc = wqs + gh*HD;
    outq = qq + (size_t)gh*TT*HD; outs = qsc_out + (size_t)gh*TT; doRope = true;
  } else if (gh < NH + NKV) {
    int hh = gh - NH;
    wgt = qwk + (size_t)hh*HD*DD; wsc = wks + hh*HD;
    outq = kq + (size_t)hh*TT*HD; outs = ksc_out + (size_t)hh*TT; doRope = true;
  } else {
    int hh = gh - NH - NKV;
    wgt = qwv + (size_t)hh*HD*DD; wsc = wvs + hh*HD;
    outq = vq + (size_t)hh*TT*HD; outs = vsc_out + (size_t)hh*TT; doRope = false;
  }

  __shared__ int8_t As[64 * 144];    // [t][k], 144B row stride
  __shared__ int8_t Bs[128 * 144];   // [o][k]
  int tid = threadIdx.x;
  int w  = tid >> 6;    // wave: t rows w*32 .. +31
  int l  = tid & 63;
  int lg = l & 15;
  int lh = l >> 4;

  i32x4 acc[2][8];
  #pragma unroll
  for (int ti = 0; ti < 2; ++ti)
    #pragma unroll
    for (int tj = 0; tj < 8; ++tj) acc[ti][tj] = (i32x4){0,0,0,0};

  i32x4 prefA[4], prefB[8];

#define PROJ_ISSUE(KT)                                                          \
  {                                                                             \
    int kk0 = (KT) * 128;                                                       \
    _Pragma("unroll")                                                           \
    for (int i = 0; i < 4; ++i) {                                               \
      int idx = tid + i*128, r = idx >> 3, c = idx & 7;                         \
      prefA[i] = *(const i32x4*)&qx[(size_t)(t0 + r)*DD + kk0 + c*16];          \
    }                                                                           \
    _Pragma("unroll")                                                           \
    for (int i = 0; i < 8; ++i) {                                               \
      int idx = tid + i*128, r = idx >> 3, c = idx & 7;                         \
      prefB[i] = *(const i32x4*)&wgt[(size_t)r*DD + kk0 + c*16];                \
    }                                                                           \
  }

  PROJ_ISSUE(0);

  for (int kt = 0; kt < DD/128; ++kt) {
    __syncthreads();   // prev compute done with As/Bs
    #pragma unroll
    for (int i = 0; i < 4; ++i) {
      int idx = tid + i*128, r = idx >> 3, c = idx & 7;
      *(i32x4*)&As[r*144 + c*16] = prefA[i];
    }
    #pragma unroll
    for (int i = 0; i < 8; ++i) {
      int idx = tid + i*128, r = idx >> 3, c = idx & 7;
      *(i32x4*)&Bs[r*144 + c*16] = prefB[i];
    }
    __syncthreads();
    if (kt + 1 < DD/128) PROJ_ISSUE(kt + 1);

    #pragma unroll
    for (int s = 0; s < 2; ++s) {
      i32x4 a0 = *(const i32x4*)&As[(w*32 + lg)*144      + s*64 + lh*16];
      i32x4 a1 = *(const i32x4*)&As[(w*32 + 16 + lg)*144 + s*64 + lh*16];
      #pragma unroll
      for (int tj = 0; tj < 8; ++tj) {
        i32x4 b = *(const i32x4*)&Bs[(tj*16 + lg)*144 + s*64 + lh*16];
        acc[0][tj] = mfma_i8(a0, b, acc[0][tj]);
        acc[1][tj] = mfma_i8(a1, b, acc[1][tj]);
      }
    }
  }
#undef PROJ_ISSUE

  // ---- epilogue: dequant -> RoPE -> rowwise requant (verified structure) ----
  float y[2][8][4];
  #pragma unroll
  for (int ti = 0; ti < 2; ++ti)
    #pragma unroll
    for (int rr = 0; rr < 4; ++rr) {
      int tl = w*32 + ti*16 + lh*4 + rr;
      float xsi = xs[t0 + tl];
      #pragma unroll
      for (int tj = 0; tj < 8; ++tj)
        y[ti][tj][rr] = (float)acc[ti][tj][rr] * xsi * wsc[tj*16 + lg];
    }

  if (doRope) {
    float invf[4];
    #pragma unroll
    for (int tj = 0; tj < 4; ++tj)
      invf[tj] = 1.0f / powf(1000000.0f, (float)(tj*16 + lg) * (1.0f/64.0f));
    #pragma unroll
    for (int ti = 0; ti < 2; ++ti)
      #pragma unroll
      for (int rr = 0; rr < 4; ++rr) {
        float trow = (float)(t0 + w*32 + ti*16 + lh*4 + rr);
        #pragma unroll
        for (int tj = 0; tj < 4; ++tj) {
          float sn, cs;
          sincosf(trow * invf[tj], &sn, &cs);
          float lo = y[ti][tj][rr], hi = y[ti][tj+4][rr];
          y[ti][tj][rr]   = lo*cs - hi*sn;
          y[ti][tj+4][rr] = hi*cs + lo*sn;
        }
      }
  }

  __syncthreads();   // all waves done reading As/Bs; reuse As for output tile
  #pragma unroll
  for (int ti = 0; ti < 2; ++ti)
    #pragma unroll
    for (int rr = 0; rr < 4; ++rr) {
      int tl = w*32 + ti*16 + lh*4 + rr;
      float mx = fabsf(y[ti][0][rr]);
      #pragma unroll
      for (int tj = 1; tj < 8; ++tj) mx = fmaxf(mx, fabsf(y[ti][tj][rr]));
      mx = fmaxf(mx, __shfl_xor(mx, 1));
      mx = fmaxf(mx, __shfl_xor(mx, 2));
      mx = fmaxf(mx, __shfl_xor(mx, 4));
      mx = fmaxf(mx, __shfl_xor(mx, 8));
      float s = fmaxf(mx / 127.0f, 1e-8f);
      if (lg == 0) outs[t0 + tl] = s;
      #pragma unroll
      for (int tj = 0; tj < 8; ++tj) {
        int qv = (int)fminf(fmaxf(rintf(y[ti][tj][rr] / s), -127.0f), 127.0f);
        As[tl*144 + tj*16 + lg] = (int8_t)qv;
      }
    }
  __syncthreads();
  #pragma unroll
  for (int i = 0; i < 4; ++i) {
    int idx = tid + i*128, r = idx >> 3, c = idx & 7;
    *(i32x4*)&outq[(size_t)(t0 + r)*HD + c*16] = *(const i32x4*)&As[r*144 + c*16];
  }
}

// ---------------------------------------------------------------------------
// Kernel 3: MFMA flash attention, operand-swapped, K-split, reg-prefetch.
// (unchanged from round 5 — verified)
// ---------------------------------------------------------------------------
__global__ __launch_bounds__(256)
void attn_mfma_kernel(const int8_t* __restrict__ qq, const float* __restrict__ qsc_in,
                      const int8_t* __restrict__ kq, const float* __restrict__ ksc_in,
                      const int8_t* __restrict__ vq, const float* __restrict__ vsc_in,
                      ushort* __restrict__ aoh, ushort* __restrict__ aol,
                      float* __restrict__ opart0, float* __restrict__ opart1,
                      float* __restrict__ mlm, float* __restrict__ mll) {
  int id = blockIdx.x;
  int h, qb, sp, ktb, kte;
  if (id < 512) {
    sp = id & 1;
    int r = id >> 1;
    h  = r & 15;
    qb = 31 - (r >> 4);
    int nkt = qb + 1, mid = nkt >> 1;
    ktb = sp ? mid : 0;
    kte = sp ? nkt : mid;
  } else {
    int r = id - 512;
    h  = r & 15;
    qb = 15 - (r >> 4);
    sp = -1;
    ktb = 0; kte = qb + 1;
  }
  int hk  = h >> 2;
  int qb0 = qb * 64;
  int nkt_full = qb + 1;

  __shared__ int8_t Ks[64 * 144];
  __shared__ ushort Vt[128 * 72];
  __shared__ float  Pf[4][16 * 68];

  int tid = threadIdx.x;
  int w  = tid >> 6;
  int l  = tid & 63;
  int lg = l & 15;
  int lh = l >> 4;

  const int8_t* qp = &qq[((size_t)h*TT + qb0 + 16*w + lg)*HD + lh*16];
  i32x4 qa0 = *(const i32x4*)qp;
  i32x4 qa1 = *(const i32x4*)(qp + 64);

  int myq = qb0 + 16*w + lg;
  float qsl = qsc_in[(size_t)h*TT + myq] * (SCALE_F * LOG2E);

  float mrun = -1e30f, lrun = 0.f;
  f32x4 acc_o[8];
  #pragma unroll
  for (int dt = 0; dt < 8; ++dt) acc_o[dt] = (f32x4){0.f, 0.f, 0.f, 0.f};

  i32x4 kreg[2];
  int2  vreg[2][2];

#define ISSUE_LOADS(KT)                                                         \
  {                                                                             \
    int kk0 = (KT) * 64;                                                        \
    _Pragma("unroll")                                                           \
    for (int i = 0; i < 2; ++i) {                                               \
      int a = tid + i*256, r = a >> 3, c = a & 7;                               \
      kreg[i] = *(const i32x4*)&kq[((size_t)hk*TT + kk0 + r)*HD + c*16];        \
    }                                                                           \
    _Pragma("unroll")                                                           \
    for (int it = 0; it < 2; ++it) {                                            \
      int a2 = tid + it*256, m2 = a2 & 31, d0 = (a2 >> 5) * 8;                  \
      vreg[it][0] = *(const int2*)&vq[((size_t)hk*TT + kk0 + 2*m2    )*HD + d0];\
      vreg[it][1] = *(const int2*)&vq[((size_t)hk*TT + kk0 + 2*m2 + 1)*HD + d0];\
    }                                                                           \
  }

  ISSUE_LOADS(ktb);

  for (int kt = ktb; kt < kte; ++kt) {
    int k0 = kt * 64;
    __syncthreads();
    #pragma unroll
    for (int i = 0; i < 2; ++i) {
      int a = tid + i*256, r = a >> 3, c = a & 7;
      *(i32x4*)&Ks[r*144 + c*16] = kreg[i];
    }
    #pragma unroll
    for (int it = 0; it < 2; ++it) {
      int a2 = tid + it*256, m2 = a2 & 31, d0 = (a2 >> 5) * 8;
      int xa = vreg[it][0].x, ya = vreg[it][0].y;
      int xb = vreg[it][1].x, yb = vreg[it][1].y;
      #pragma unroll
      for (int j = 0; j < 4; ++j) {
        int v0 = (xa << (24 - 8*j)) >> 24;
        int v1 = (xb << (24 - 8*j)) >> 24;
        uint32_t pk = (fbits((float)v0) >> 16) | ((fbits((float)v1) >> 16) << 16);
        *(uint32_t*)&Vt[(d0 + j)*72 + 2*m2] = pk;
      }
      #pragma unroll
      for (int j = 0; j < 4; ++j) {
        int v0 = (ya << (24 - 8*j)) >> 24;
        int v1 = (yb << (24 - 8*j)) >> 24;
        uint32_t pk = (fbits((float)v0) >> 16) | ((fbits((float)v1) >> 16) << 16);
        *(uint32_t*)&Vt[(d0 + 4 + j)*72 + 2*m2] = pk;
      }
    }
    __syncthreads();
    if (kt + 1 < kte) ISSUE_LOADS(kt + 1);

    i32x4 sacc[4];
    #pragma unroll
    for (int t = 0; t < 4; ++t) sacc[t] = (i32x4){0, 0, 0, 0};
    #pragma unroll
    for (int t = 0; t < 4; ++t) {
      const int8_t* kp = &Ks[(16*t + lg)*144 + lh*16];
      i32x4 b0 = *(const i32x4*)kp;
      i32x4 b1 = *(const i32x4*)(kp + 64);
      sacc[t] = mfma_i8(b0, qa0, sacc[t]);
      sacc[t] = mfma_i8(b1, qa1, sacc[t]);
    }

    f32x4 ksv4[4], vsv4[4];
    #pragma unroll
    for (int t = 0; t < 4; ++t) {
      ksv4[t] = *(const f32x4*)&ksc_in[(size_t)hk*TT + k0 + 16*t + 4*lh];
      vsv4[t] = *(const f32x4*)&vsc_in[(size_t)hk*TT + k0 + 16*t + 4*lh];
    }

    bool maskTile = (kt == nkt_full - 1);
    float sf[4][4];
    #pragma unroll
    for (int t = 0; t < 4; ++t)
      #pragma unroll
      for (int rr = 0; rr < 4; ++rr) {
        float v = (float)sacc[t][rr] * qsl * ksv4[t][rr];
        if (maskTile) {
          int kkg = k0 + 16*t + 4*lh + rr;
          v = (kkg <= myq) ? v : -1e30f;
        }
        sf[t][rr] = v;
      }

    float rm = sf[0][0];
    #pragma unroll
    for (int t = 0; t < 4; ++t)
      #pragma unroll
      for (int rr = 0; rr < 4; ++rr) rm = fmaxf(rm, sf[t][rr]);
    rm = fmaxf(rm, __shfl_xor(rm, 16));
    rm = fmaxf(rm, __shfl_xor(rm, 32));
    float mnew = fmaxf(mrun, rm);
    float corr = EXP2(mrun - mnew);
    mrun = mnew;
    float p[4][4];
    float ps = 0.f;
    #pragma unroll
    for (int t = 0; t < 4; ++t)
      #pragma unroll
      for (int rr = 0; rr < 4; ++rr) { p[t][rr] = EXP2(sf[t][rr] - mnew); ps += p[t][rr]; }
    ps += __shfl_xor(ps, 16);
    ps += __shfl_xor(ps, 32);
    lrun = lrun * corr + ps;

    #pragma unroll
    for (int t = 0; t < 4; ++t) {
      f32x4 pw;
      #pragma unroll
      for (int rr = 0; rr < 4; ++rr) pw[rr] = p[t][rr] * vsv4[t][rr];
      *(f32x4*)&Pf[w][lg*68 + 16*t + 4*lh] = pw;
    }

    #pragma unroll
    for (int dt = 0; dt < 8; ++dt)
      #pragma unroll
      for (int rr = 0; rr < 4; ++rr) acc_o[dt][rr] *= corr;

    s16x8 pahi[2], palo[2];
    #pragma unroll
    for (int kb = 0; kb < 2; ++kb) {
      const float* pr = &Pf[w][lg*68 + kb*32 + lh*8];
      f32x4 x0 = *(const f32x4*)pr;
      f32x4 x1 = *(const f32x4*)(pr + 4);
      float xv[8] = {x0.x, x0.y, x0.z, x0.w, x1.x, x1.y, x1.z, x1.w};
      float lv[8];
      #pragma unroll
      for (int j = 0; j < 8; ++j) {
        uint32_t hb = fbits(xv[j]) & 0xffff0000u;
        union { uint32_t u; float f; } hf; hf.u = hb;
        lv[j] = xv[j] - hf.f;
      }
      union { uint32_t u[4]; s16x8 v; } H, L;
      #pragma unroll
      for (int jj = 0; jj < 4; ++jj) {
        H.u[jj] = (fbits(xv[2*jj]) >> 16) | (fbits(xv[2*jj+1]) & 0xffff0000u);
        L.u[jj] = (fbits(lv[2*jj]) >> 16) | (fbits(lv[2*jj+1]) & 0xffff0000u);
      }
      pahi[kb] = H.v; palo[kb] = L.v;
    }

    #pragma unroll
    for (int dt = 0; dt < 8; ++dt) {
      #pragma unroll
      for (int kb = 0; kb < 2; ++kb) {
        s16x8 vb = *(const s16x8*)&Vt[(16*dt + lg)*72 + kb*32 + lh*8];
        acc_o[dt] = mfma_bf16(vb, pahi[kb], acc_o[dt]);
        acc_o[dt] = mfma_bf16(vb, palo[kb], acc_o[dt]);
      }
    }
  }
#undef ISSUE_LOADS

  if (sp < 0) {
    float invv = 1.0f / lrun;
    size_t base = (size_t)myq*DD + (size_t)h*HD;
    #pragma unroll
    for (int dt = 0; dt < 8; ++dt) {
      ushort4 Hv, Lv;
      float v0 = acc_o[dt][0]*invv, v1 = acc_o[dt][1]*invv;
      float v2 = acc_o[dt][2]*invv, v3 = acc_o[dt][3]*invv;
      Hv.x = bf16_rne(v0); Hv.y = bf16_rne(v1); Hv.z = bf16_rne(v2); Hv.w = bf16_rne(v3);
      Lv.x = bf16_rne(v0 - bf16_to_f(Hv.x)); Lv.y = bf16_rne(v1 - bf16_to_f(Hv.y));
      Lv.z = bf16_rne(v2 - bf16_to_f(Hv.z)); Lv.w = bf16_rne(v3 - bf16_to_f(Hv.w));
      *(ushort4*)&aoh[base + 16*dt + 4*lh] = Hv;
      *(ushort4*)&aol[base + 16*dt + 4*lh] = Lv;
    }
  } else {
    int tile = h*16 + (qb - 16);
    float* op = (sp == 0 ? opart0 : opart1) + (size_t)tile*8192 + (size_t)(16*w + lg)*128;
    #pragma unroll
    for (int dt = 0; dt < 8; ++dt)
      *(f32x4*)&op[16*dt + 4*lh] = acc_o[dt];
    if (lh == 0) {
      mlm[sp*16384 + tile*64 + 16*w + lg] = mrun;
      mll[sp*16384 + tile*64 + 16*w + lg] = lrun;
    }
  }
}

// ---------------------------------------------------------------------------
// Kernel 3b: merge the two K-split halves for qb >= 16.
// ---------------------------------------------------------------------------
__global__ __launch_bounds__(256)
void merge_kernel(const float* __restrict__ opart0, const float* __restrict__ opart1,
                  const float* __restrict__ mlm, const float* __restrict__ mll,
                  ushort* __restrict__ aoh, ushort* __restrict__ aol) {
  int tile = blockIdx.x;
  int h = tile >> 4, j = tile & 15;
  int tid = threadIdx.x;
  int row = tid >> 2;
  int cseg = (tid & 3) * 32;
  float m1 = mlm[tile*64 + row], m2 = mlm[16384 + tile*64 + row];
  float l1 = mll[tile*64 + row], l2 = mll[16384 + tile*64 + row];
  float m = fmaxf(m1, m2);
  float c1 = EXP2(m1 - m), c2 = EXP2(m2 - m);
  float inv = 1.0f / (l1*c1 + l2*c2);
  const float* p0 = opart0 + (size_t)tile*8192 + row*128 + cseg;
  const float* p1 = opart1 + (size_t)tile*8192 + row*128 + cseg;
  size_t ob = (size_t)(1024 + j*64 + row)*DD + (size_t)h*HD + cseg;
  #pragma unroll
  for (int c4 = 0; c4 < 8; ++c4) {
    f32x4 a = *(const f32x4*)&p0[c4*4];
    f32x4 b = *(const f32x4*)&p1[c4*4];
    ushort4 Hv, Lv;
    #pragma unroll
    for (int e = 0; e < 4; ++e) {
      float v = (a[e]*c1 + b[e]*c2) * inv;
      ushort hb = bf16_rne(v);
      ushort lb = bf16_rne(v - bf16_to_f(hb));
      ((ushort*)&Hv)[e] = hb;
      ((ushort*)&Lv)[e] = lb;
    }
    *(ushort4*)&aoh[ob + c4*4] = Hv;
    *(ushort4*)&aol[ob + c4*4] = Lv;
  }
}

// ---------------------------------------------------------------------------
// Kernel 3c: split wo (f32) into hi/lo bf16.
// ---------------------------------------------------------------------------
__global__ __launch_bounds__(256)
void wcvt_kernel(const float* __restrict__ wom, ushort* __restrict__ woh,
                 ushort* __restrict__ wol) {
  size_t base = ((size_t)blockIdx.x * 256 + threadIdx.x) * 8;
  float4 a = *(const float4*)&wom[base];
  float4 b = *(const float4*)&wom[base + 4];
  float vv[8] = {a.x, a.y, a.z, a.w, b.x, b.y, b.z, b.w};
  s16x8 H, L;
  #pragma unroll
  for (int j = 0; j < 8; ++j) {
    ushort hb = bf16_rne(vv[j]);
    float lo = vv[j] - bf16_to_f(hb);
    H[j] = (short)hb;
    L[j] = (short)bf16_rne(lo);
  }
  *(s16x8*)&woh[base] = H;
  *(s16x8*)&wol[base] = L;
}

// ---------------------------------------------------------------------------
// Kernel 4: wo GEMM on bf16 MFMA with 3-product split (unchanged, verified).
// ---------------------------------------------------------------------------
__global__ __launch_bounds__(256)
void wo_gemm_kernel(const ushort* __restrict__ aoh, const ushort* __restrict__ aol,
                    const ushort* __restrict__ woh, const ushort* __restrict__ wol,
                    float* __restrict__ outp) {
  int o0 = blockIdx.x * 128;
  int t0 = blockIdx.y * 128;
  __shared__ ushort AH[128 * 72];
  __shared__ ushort AL[128 * 72];
  __shared__ ushort BH[128 * 72];
  __shared__ ushort BL[128 * 72];
  int tid = threadIdx.x;
  int wv4 = tid >> 6;
  int wr = wv4 >> 1, wc = wv4 & 1;
  int l  = tid & 63;
  int lg = l & 15;
  int lh = l >> 4;

  f32x4 acc[4][4];
  #pragma unroll
  for (int ti = 0; ti < 4; ++ti)
    #pragma unroll
    for (int tj = 0; tj < 4; ++tj) acc[ti][tj] = (f32x4){0.f,0.f,0.f,0.f};

  for (int kt = 0; kt < DD/64; ++kt) {
    int k0 = kt * 64;
    __syncthreads();
    #pragma unroll
    for (int i = 0; i < 4; ++i) {
      int idx = tid + i*256, r = idx >> 3, c = idx & 7;
      size_t ga = (size_t)(t0 + r)*DD + k0 + c*8;
      size_t gb = (size_t)(o0 + r)*DD + k0 + c*8;
      *(s16x8*)&AH[r*72 + c*8] = *(const s16x8*)&aoh[ga];
      *(s16x8*)&AL[r*72 + c*8] = *(const s16x8*)&aol[ga];
      *(s16x8*)&BH[r*72 + c*8] = *(const s16x8*)&woh[gb];
      *(s16x8*)&BL[r*72 + c*8] = *(const s16x8*)&wol[gb];
    }
    __syncthreads();
    #pragma unroll
    for (int s = 0; s < 2; ++s) {
      s16x8 ah[4], al[4];
      #pragma unroll
      for (int ti = 0; ti < 4; ++ti) {
        int ab = (wr*64 + ti*16 + lg)*72 + s*32 + lh*8;
        ah[ti] = *(const s16x8*)&AH[ab];
        al[ti] = *(const s16x8*)&AL[ab];
      }
      #pragma unroll
      for (int tj = 0; tj < 4; ++tj) {
        int bb = (wc*64 + tj*16 + lg)*72 + s*32 + lh*8;
        s16x8 bh = *(const s16x8*)&BH[bb];
        s16x8 bl = *(const s16x8*)&BL[bb];
        #pragma unroll
        for (int ti = 0; ti < 4; ++ti) {
          acc[ti][tj] = mfma_bf16(ah[ti], bh, acc[ti][tj]);
          acc[ti][tj] = mfma_bf16(ah[ti], bl, acc[ti][tj]);
          acc[ti][tj] = mfma_bf16(al[ti], bh, acc[ti][tj]);
        }
      }
    }
  }

  #pragma unroll
  for (int ti = 0; ti < 4; ++ti)
    #pragma unroll
    for (int tj = 0; tj < 4; ++tj)
      #pragma unroll
      for (int rr = 0; rr < 4; ++rr) {
        int t = t0 + wr*64 + ti*16 + lh*4 + rr;
        int o = o0 + wc*64 + tj*16 + lg;
        outp[(size_t)t*DD + o] = acc[ti][tj][rr];
      }
}

// ---------------------------------------------------------------------------
extern "C" void kernel_launch(void* const* d_in, const int* in_sizes, int n_in,
                              void* d_out, int out_size, void* d_ws, size_t ws_size,
                              hipStream_t stream) {
  (void)in_sizes; (void)n_in; (void)out_size; (void)ws_size;
  const float* x  = (const float*)d_in[0];
  const float* wq = (const float*)d_in[1];
  const float* wk = (const float*)d_in[2];
  const float* wv = (const float*)d_in[3];
  const float* wo = (const float*)d_in[4];
  float* out = (float*)d_out;

  char* ws = (char*)d_ws;
  const size_t MB = 1048576;
  int8_t* qx  = (int8_t*)(ws);           // [2048][2048]; dead after proj
  int8_t* qwq = (int8_t*)(ws + 4*MB);    // dead after proj
  int8_t* qwk = (int8_t*)(ws + 8*MB);    // dead after proj
  int8_t* qwv = (int8_t*)(ws + 9*MB);    // dead after proj
  int8_t* qqp = (int8_t*)(ws + 10*MB);   // [16][2048][128]; dead after attn
  int8_t* kqp = (int8_t*)(ws + 14*MB);   // [4][2048][128];  dead after attn
  int8_t* vqp = (int8_t*)(ws + 15*MB);   // [4][2048][128];  dead after attn
  float* xs  = (float*)(ws + 16*MB);
  float* wqs = xs + 2048;
  float* wks = wqs + 2048;
  float* wvs = wks + 512;
  float* qsc = wvs + 512;
  float* ksc = qsc + (size_t)NH*TT;
  float* vsc = ksc + (size_t)NKV*TT;
  ushort* aoh = (ushort*)(ws + 16*MB + 262144);   // 8 MB
  ushort* aol = (ushort*)(ws + 24*MB + 262144);   // 8 MB (ends 32.25 MB)
  // attn-phase scratch over dead regions:
  float* opart0 = (float*)(ws);                   // 8 MiB (over qx/qwq, dead)
  float* mlm    = (float*)(ws + 8*MB);            // 128 KB (over qwk, dead)
  float* mll    = (float*)(ws + 8*MB + 131072);   // 128 KB
  float* opart1 = out;                            // 8 MiB scratch in d_out
  // wo-phase scratch (after merge, everything below 16 MB is dead):
  ushort* woh = (ushort*)(ws);                    // 8 MB
  ushort* wol = (ushort*)(ws + 8*MB);             // 8 MB

  quant_rows_kernel<<<5120, 256, 0, stream>>>(x, wq, wk, wv,
                                              qx, xs, qwq, wqs, qwk, wks, qwv, wvs);
  proj_kernel<<<768, 128, 0, stream>>>(
      qx, xs, qwq, wqs, qwk, wks, qwv, wvs,
      qqp, qsc, kqp, ksc, vqp, vsc);
  attn_mfma_kernel<<<768, 256, 0, stream>>>(
      qqp, qsc, kqp, ksc, vqp, vsc, aoh, aol, opart0, opart1, mlm, mll);
  merge_kernel<<<256, 256, 0, stream>>>(opart0, opart1, mlm, mll, aoh, aol);
  wcvt_kernel<<<2048, 256, 0, stream>>>(wo, woh, wol);
  wo_gemm_kernel<<<dim3(DD/128, TT/128), 256, 0, stream>>>(aoh, aol, woh, wol, out);
}